// Round 11
// baseline (619.844 us; speedup 1.0000x reference)
//
#include <hip/hip_runtime.h>
#include <math.h>

#define N_NODES 50000
#define N_EDGES 800000
#define NGRAPH  64
#define KEFF    576   // compressed agg width (768->576 via x_dst folding)

typedef short bf16x8 __attribute__((ext_vector_type(8)));
typedef float f32x4  __attribute__((ext_vector_type(4)));
typedef float f32x16 __attribute__((ext_vector_type(16)));
typedef unsigned int u32;
typedef unsigned int u32x4 __attribute__((ext_vector_type(4)));

__device__ inline unsigned short f2bf_rne(float f) {
  unsigned u = __float_as_uint(f);
  unsigned r = u + 0x7FFFu + ((u >> 16) & 1u);
  return (unsigned short)(r >> 16);
}
__device__ inline float bf2f(unsigned short h) {
  return __uint_as_float(((unsigned)h) << 16);
}

// packed bf16 convert (RNE): dst.lo16 = bf16(a), dst.hi16 = bf16(b)
__device__ inline u32 cvtpk_bf16(float a, float b) {
  u32 r;
  asm("v_cvt_pk_bf16_f32 %0, %1, %2" : "=v"(r) : "v"(a), "v"(b));
  return r;
}

// hi/lo split of a float pair into packed bf16 words.
// lo = v - float(hi) is exact in fp32 (<=17 significant bits).
__device__ inline void split2(float a, float b, u32& ph, u32& pl) {
  ph = cvtpk_bf16(a, b);
  float ha = __uint_as_float(ph << 16);
  float hb = __uint_as_float(ph & 0xFFFF0000u);
  pl = cvtpk_bf16(a - ha, b - hb);
}

__device__ inline bf16x8 pack_bf(u32 w0, u32 w1, u32 w2, u32 w3) {
  u32x4 t;
  t.x = w0; t.y = w1; t.z = w2; t.w = w3;
  return __builtin_bit_cast(bf16x8, t);
}

// ===================== setup kernels =====================

// one kernel zeroes everything (replaces 4 memset dispatches)
__global__ __launch_bounds__(256) void zero_kernel(
    int* __restrict__ cnt, float* __restrict__ gsum,
    double* __restrict__ bnacc, double* __restrict__ avgacc)
{
  int i = blockIdx.x * 256 + threadIdx.x;   // grid 213 -> 54528
  if (i < N_NODES) { cnt[i] = 0; return; }
  int j = i - N_NODES;
  if (j < NGRAPH * 64) { gsum[j] = 0.f; return; }
  int k = j - NGRAPH * 64;
  if (k < 3 * 128) { bnacc[k] = 0.0; return; }
  if (k == 3 * 128) *avgacc = 0.0;
}

__global__ __launch_bounds__(256) void node_enc_kernel(
    const float* __restrict__ xin, const float* __restrict__ nw,
    const float* __restrict__ nb, float* __restrict__ x)
{
  __shared__ float xs[256];
  int tid = threadIdx.x;
  int base = blockIdx.x * 256;          // 4 nodes per block
  xs[tid] = xin[base + tid];
  __syncthreads();
  int r = tid >> 6, j = tid & 63;
  float acc = nb[j];
#pragma unroll
  for (int t = 0; t < 64; t++) acc = fmaf(xs[r * 64 + t], nw[t * 64 + j], acc);
  x[base + tid] = acc;
}

// count + within-node rank: the same atomic that counts gives each edge its
// slot; fill then needs NO atomic (rank written coalesced, 3.2MB).
__global__ void count_kernel(const int* __restrict__ dst, int* __restrict__ cnt,
                             int* __restrict__ rank)
{
  int e = blockIdx.x * 256 + threadIdx.x;   // grid exactly covers E
  rank[e] = atomicAdd(&cnt[dst[e]], 1);
}

// merged scan_a + deg_log: both read cnt with the same grid (196 blocks)
__global__ __launch_bounds__(256) void scan_deg_kernel(
    const int* __restrict__ cnt, int* __restrict__ bsum,
    float* __restrict__ log_deg, double* __restrict__ avgacc)
{
  __shared__ int s[256];
  __shared__ double sb[256];
  int tid = threadIdx.x;
  int i = blockIdx.x * 256 + tid;
  int v = (i < N_NODES) ? cnt[i] : 0;
  s[tid] = v;
  double c = 0.0;
  if (i < N_NODES) {
    int dc = v > 0 ? v : 1;
    log_deg[i] = logf((float)dc + 1.0f);         // log(degc + 1)
    c = (double)logf((float)v + 1.0f);           // avg uses raw deg
  }
  sb[tid] = c;
  __syncthreads();
  for (int off = 128; off > 0; off >>= 1) {
    if (tid < off) { s[tid] += s[tid + off]; sb[tid] += sb[tid + off]; }
    __syncthreads();
  }
  if (tid == 0) { bsum[blockIdx.x] = s[0]; atomicAdd(avgacc, sb[0]); }
}

__global__ __launch_bounds__(256) void scan_b_kernel(
    const int* __restrict__ bsum, int* __restrict__ boff)
{
  __shared__ int s[256];
  int tid = threadIdx.x;
  int v = (tid < 196) ? bsum[tid] : 0;
  s[tid] = v;
  __syncthreads();
  for (int off = 1; off < 256; off <<= 1) {
    int t = (tid >= off) ? s[tid - off] : 0;
    __syncthreads();
    s[tid] += t;
    __syncthreads();
  }
  boff[tid] = s[tid] - v;   // exclusive prefix of block sums
}

__global__ __launch_bounds__(256) void scan_c_kernel(
    const int* __restrict__ cnt, const int* __restrict__ boff,
    int* __restrict__ row_ptr)
{
  __shared__ int s[256];
  int tid = threadIdx.x;
  int i = blockIdx.x * 256 + tid;
  int v = (i < N_NODES) ? cnt[i] : 0;
  s[tid] = v;
  __syncthreads();
  for (int off = 1; off < 256; off <<= 1) {
    int t = (tid >= off) ? s[tid - off] : 0;
    __syncthreads();
    s[tid] += t;
    __syncthreads();
  }
  int incl = s[tid];
  int base = boff[blockIdx.x];
  if (i < N_NODES) row_ptr[i] = base + incl - v;
  if (i == N_NODES - 1) row_ptr[N_NODES] = base + incl;
}

// CSR fill, atomic-free: pos = row_ptr[dst] + rank. Single 8B scattered
// store per edge (src,eid packed) -> half the partial-line merge traffic of
// the old two-array version (WRITE_SIZE was 83MB for 6.4MB payload).
__global__ void fill_kernel(const int* __restrict__ src, const int* __restrict__ dst,
                            const int* __restrict__ rank, const int* __restrict__ row_ptr,
                            int2* __restrict__ edata)
{
  int e = blockIdx.x * 256 + threadIdx.x;
  int d = dst[e];
  int pos = row_ptr[d] + rank[e];
  edata[pos] = make_int2(src[e], e);
}

// fused: avg finalize + graph bounds (binary search on sorted batch)
__global__ void avg_gb_kernel(const double* __restrict__ avgacc,
                              float* __restrict__ avgf,
                              const int* __restrict__ batch,
                              int* __restrict__ gcnt)
{
  __shared__ int sb[65];
  int g = threadIdx.x;  // 64 threads
  int lo = 0, hi = N_NODES;
  while (lo < hi) { int mid = (lo + hi) >> 1; if (batch[mid] < g) lo = mid + 1; else hi = mid; }
  sb[g] = lo;
  if (g == 0) { sb[64] = N_NODES; *avgf = (float)(*avgacc / (double)N_NODES); }
  __syncthreads();
  gcnt[g] = sb[g + 1] - sb[g];
}

// ===================== merged weight prep (wprep + bprep + ewprep) =========
// blocks [0,1296): conv_w fold + bf16 hi/lo MFMA-swizzle (B layout:
// [l][cg=c/16][kc=k/8][c15=c%16][ko=k%8]); block 1296: beff; block 1297:
// edge_w 32x32 B-fragments (2 x 2KB, L2-resident).

__global__ __launch_bounds__(256) void prep_kernel(
    const float* __restrict__ conv_w, const float* __restrict__ edge_w,
    unsigned short* __restrict__ wh, unsigned short* __restrict__ wl,
    float* __restrict__ beff,
    unsigned short* __restrict__ ewh, unsigned short* __restrict__ ewl)
{
  int b = blockIdx.x, tid = threadIdx.x;
  if (b < 1296) {
    int idx = b * 256 + tid;            // 3*192*576 = 331776 = 1296*256
    int k = idx % 576;
    int c = (idx / 576) % 192;
    int l = idx / (576 * 192);
    int s = c >> 6, j = c & 63;
    const float* CW = conv_w + (size_t)l * 2304 * 64;
    float v;
    if (k < 64) {
      int base = s * 768 + k;
      v = CW[base * 64 + j] + CW[(base + 192) * 64 + j] + CW[(base + 384) * 64 + j];
    } else {
      const int srcseg[8] = {1, 2, 4, 5, 7, 8, 10, 11};
      int q = (k >> 6) - 1;
      int t = k & 63;
      v = CW[(s * 768 + srcseg[q] * 64 + t) * 64 + j];
    }
    unsigned short hh = f2bf_rne(v);
    size_t o = (((size_t)l * 12 + (c >> 4)) * 72 + (k >> 3)) * 128 + (c & 15) * 8 + (k & 7);
    wh[o] = hh;
    wl[o] = f2bf_rne(v - bf2f(hh));
  } else if (b == 1296) {
    if (tid < 192) {
      int s = tid >> 6, j = tid & 63;
#pragma unroll
      for (int l = 0; l < 3; l++) {
        const float* CW = conv_w + (size_t)l * 2304 * 64 + (size_t)(s * 768 + 576) * 64;
        float sum = 0.f;
#pragma unroll
        for (int t = 0; t < 64; t++) sum += CW[t * 64 + j];
        beff[(l * 3 + s) * 64 + j] = sum * 0.0031622776601683794f;   // sqrt(1e-5)
      }
    }
  } else {
#pragma unroll
    for (int it = 0; it < 4; it++) {
      int idx = tid + 256 * it;        // 1024 total
      int j = idx & 7, cb = (idx >> 3) & 1, l31 = (idx >> 4) & 31, hf = idx >> 9;
      float v = edge_w[(hf * 8 + j) * 64 + cb * 32 + l31];
      unsigned short h = f2bf_rne(v);
      ewh[idx] = h;
      ewl[idx] = f2bf_rne(v - bf2f(h));
    }
  }
}

// ===================== e-segment aggregation (layer-invariant, once) ========
// 32x32x16 MFMA edge-encoder: A = 32 edges x 16 attrs (K=16 = EA_DIM, no
// stacking), each lane loads a distinct (edge, attr-half) -> no gather
// redundancy. 3 passes (hi*Wh, lo*Wh, hi*Wl) x 2 colgroups = 6 MFMA per 32
// edges. Unified masked accumulate; clamped dup ids keep min/max safe.
// Two consecutive nodes per wave step for 2x memory-level parallelism.

#define AGG_E_BLOCKS 2048
#define AGG_E_WAVES  (AGG_E_BLOCKS * 4)

__global__ __launch_bounds__(256) void agg_e_kernel(
    const float* __restrict__ eattr,
    const unsigned short* __restrict__ ewh, const unsigned short* __restrict__ ewl,
    const float* __restrict__ edge_b, const int* __restrict__ row_ptr,
    const int2* __restrict__ edata,
    unsigned short* __restrict__ agg_h, unsigned short* __restrict__ agg_l)
{
  int lane = threadIdx.x & 63;
  int l31 = lane & 31, hf = lane >> 5;
  float eb = edge_b[lane];

  int fbase = (hf * 32 + l31) * 16;
  bf16x8 wbh[2], wbl[2];
#pragma unroll
  for (int cb = 0; cb < 2; cb++) {
    wbh[cb] = *(const bf16x8*)(ewh + fbase + cb * 8);
    wbl[cb] = *(const bf16x8*)(ewl + fbase + cb * 8);
  }

  const f32x16 zero = {};
  int wid = __builtin_amdgcn_readfirstlane(blockIdx.x * 4 + (threadIdx.x >> 6));

  auto process = [&](int n, int s0, int s1, float4 d0, float4 d1) {
    int deg = s1 - s0;
    float se[2] = {0.f, 0.f}, sq[2] = {0.f, 0.f};
    float mx[2] = {-3.4e38f, -3.4e38f}, mn[2] = {3.4e38f, 3.4e38f};
    if (deg > 0) {
      int j = s0;
      while (true) {
        int remh = (s1 - j) - 4 * hf;   // valid row: baserow < remh
        u32 h0, l0, h1, l1, h2, l2, h3, l3;
        split2(d0.x, d0.y, h0, l0); split2(d0.z, d0.w, h1, l1);
        split2(d1.x, d1.y, h2, l2); split2(d1.z, d1.w, h3, l3);
        bf16x8 ahi = pack_bf(h0, h1, h2, h3), alo = pack_bf(l0, l1, l2, l3);
#pragma unroll
        for (int cb = 0; cb < 2; cb++) {
          f32x16 acc = __builtin_amdgcn_mfma_f32_32x32x16_bf16(ahi, wbh[cb], zero, 0, 0, 0);
          acc = __builtin_amdgcn_mfma_f32_32x32x16_bf16(alo, wbh[cb], acc, 0, 0, 0);
          acc = __builtin_amdgcn_mfma_f32_32x32x16_bf16(ahi, wbl[cb], acc, 0, 0, 0);
#pragma unroll
          for (int reg = 0; reg < 16; reg++) {
            const int baserow = (reg & 3) + 8 * (reg >> 2);
            float v = acc[reg];
            float vm = (baserow < remh) ? v : 0.f;   // mask pads for sum/sumsq
            se[cb] += vm; sq[cb] = fmaf(vm, vm, sq[cb]);
            // min/max: clamped duplicates are valid edge values -> harmless
            mx[cb] = fmaxf(mx[cb], v); mn[cb] = fminf(mn[cb], v);
          }
        }
        j += 32;
        if (j >= s1) break;
        // rare continuation (deg > 32): inline gather
        int id = edata[min(j + l31, s1 - 1)].y;
        const float4* pp = (const float4*)(eattr + (size_t)id * 16 + hf * 8);
        d0 = pp[0]; d1 = pp[1];
      }
    }
    // cross-half reduce: lane l and l^32 hold same col of their cb
#pragma unroll
    for (int cb = 0; cb < 2; cb++) {
      se[cb] += __shfl_xor(se[cb], 32, 64);
      sq[cb] += __shfl_xor(sq[cb], 32, 64);
      mx[cb] = fmaxf(mx[cb], __shfl_xor(mx[cb], 32, 64));
      mn[cb] = fminf(mn[cb], __shfl_xor(mn[cb], 32, 64));
    }
    // output col for lane = hf*32 + l31 = lane -> pick cb = hf
    float SE = hf ? se[1] : se[0];
    float SQ = hf ? sq[1] : sq[0];
    float MX = hf ? mx[1] : mx[0];
    float MN = hf ? mn[1] : mn[0];

    float inv = 1.0f / fmaxf((float)deg, 1.0f);
    bool has = deg > 0;
    float m0 = SE * inv, ms0 = SQ * inv;
    // variance is bias-invariant: E[(v+b)^2] - (E[v]+b)^2 = E[v^2] - E[v]^2
    float sd_e = sqrtf(fmaxf(ms0 - m0 * m0, 0.f) + 1e-5f);
    float m_e = has ? m0 + eb : 0.f;
    float mx_e = has ? MX + eb : 0.f;
    float mn_e = has ? MN + eb : 0.f;

    unsigned short* bh = agg_h + (size_t)n * KEFF;
    unsigned short* bl = agg_l + (size_t)n * KEFF;
#define W2(off, val) { float _v = (val); unsigned short _h = f2bf_rne(_v); \
                       bh[(off) + lane] = _h; bl[(off) + lane] = f2bf_rne(_v - bf2f(_h)); }
    W2(128, m_e); W2(256, mn_e); W2(384, mx_e); W2(512, sd_e);
#undef W2
  };

  for (int p = wid; p < N_NODES / 2; p += AGG_E_WAVES) {
    int nA = 2 * p;
    int r0 = row_ptr[nA], r1 = row_ptr[nA + 1], r2 = row_ptr[nA + 2];
    // both ids gathers back-to-back, then both data gathers back-to-back
    int idA = 0, idB = 0;
    if (r1 > r0) idA = edata[min(r0 + l31, r1 - 1)].y;
    if (r2 > r1) idB = edata[min(r1 + l31, r2 - 1)].y;
    float4 da0 = {}, da1 = {}, db0 = {}, db1 = {};
    if (r1 > r0) {
      const float4* pa = (const float4*)(eattr + (size_t)idA * 16 + hf * 8);
      da0 = pa[0]; da1 = pa[1];
    }
    if (r2 > r1) {
      const float4* pb = (const float4*)(eattr + (size_t)idB * 16 + hf * 8);
      db0 = pb[0]; db1 = pb[1];
    }
    process(nA, r0, r1, da0, da1);
    process(nA + 1, r1, r2, db0, db1);
  }
}

// ===================== per-layer x-segment aggregation =====================
// x8 unroll with MASKED single-iteration tail. x_dst segment no longer
// written here: gemm reads x directly (saves 12.8MB writes/layer).

__global__ __launch_bounds__(256) void agg_x_kernel(
    const float* __restrict__ x, const int2* __restrict__ edata,
    const int* __restrict__ row_ptr,
    unsigned short* __restrict__ agg_h, unsigned short* __restrict__ agg_l)
{
  int lane = threadIdx.x & 63;
  int n = blockIdx.x * 4 + (threadIdx.x >> 6);
  if (n >= N_NODES) return;
  int s0 = row_ptr[n], s1 = row_ptr[n + 1];
  float sA = 0.f, sB = 0.f, sC = 0.f, sD = 0.f;
  float qA = 0.f, qB = 0.f, qC = 0.f, qD = 0.f;
  float mx0 = -3.4e38f, mx1 = -3.4e38f, mn0 = 3.4e38f, mn1 = 3.4e38f;
  int j = s0;
  for (; j + 7 < s1; j += 8) {
    int e0 = edata[j].x,     e1 = edata[j + 1].x, e2 = edata[j + 2].x, e3 = edata[j + 3].x;
    int e4 = edata[j + 4].x, e5 = edata[j + 5].x, e6 = edata[j + 6].x, e7 = edata[j + 7].x;
    float x0 = x[(size_t)e0 * 64 + lane];
    float x1 = x[(size_t)e1 * 64 + lane];
    float x2 = x[(size_t)e2 * 64 + lane];
    float x3 = x[(size_t)e3 * 64 + lane];
    float x4 = x[(size_t)e4 * 64 + lane];
    float x5 = x[(size_t)e5 * 64 + lane];
    float x6 = x[(size_t)e6 * 64 + lane];
    float x7 = x[(size_t)e7 * 64 + lane];
    sA += x0; sB += x1; sC += x2; sD += x3;
    sA += x4; sB += x5; sC += x6; sD += x7;
    qA = fmaf(x0, x0, qA); qB = fmaf(x1, x1, qB);
    qC = fmaf(x2, x2, qC); qD = fmaf(x3, x3, qD);
    qA = fmaf(x4, x4, qA); qB = fmaf(x5, x5, qB);
    qC = fmaf(x6, x6, qC); qD = fmaf(x7, x7, qD);
    mx0 = fmaxf(mx0, fmaxf(fmaxf(x0, x1), fmaxf(x2, x3)));
    mx1 = fmaxf(mx1, fmaxf(fmaxf(x4, x5), fmaxf(x6, x7)));
    mn0 = fminf(mn0, fminf(fminf(x0, x1), fminf(x2, x3)));
    mn1 = fminf(mn1, fminf(fminf(x4, x5), fminf(x6, x7)));
  }
  if (j < s1) {                       // masked tail: 1..7 edges, 8 gathers in flight
    int last = s1 - 1;
    int rem = s1 - j;                 // wave-uniform
    int e0 = edata[j].x;
    int e1 = edata[j + 1 < s1 ? j + 1 : last].x;
    int e2 = edata[j + 2 < s1 ? j + 2 : last].x;
    int e3 = edata[j + 3 < s1 ? j + 3 : last].x;
    int e4 = edata[j + 4 < s1 ? j + 4 : last].x;
    int e5 = edata[j + 5 < s1 ? j + 5 : last].x;
    int e6 = edata[j + 6 < s1 ? j + 6 : last].x;
    int e7 = edata[j + 7 < s1 ? j + 7 : last].x;
    float x0 = x[(size_t)e0 * 64 + lane];
    float x1 = x[(size_t)e1 * 64 + lane];
    float x2 = x[(size_t)e2 * 64 + lane];
    float x3 = x[(size_t)e3 * 64 + lane];
    float x4 = x[(size_t)e4 * 64 + lane];
    float x5 = x[(size_t)e5 * 64 + lane];
    float x6 = x[(size_t)e6 * 64 + lane];
    float x7 = x[(size_t)e7 * 64 + lane];
    // min/max: clamped duplicates are valid edge values -> harmless
    mx0 = fmaxf(mx0, fmaxf(fmaxf(x0, x1), fmaxf(x2, x3)));
    mx1 = fmaxf(mx1, fmaxf(fmaxf(x4, x5), fmaxf(x6, x7)));
    mn0 = fminf(mn0, fminf(fminf(x0, x1), fminf(x2, x3)));
    mn1 = fminf(mn1, fminf(fminf(x4, x5), fminf(x6, x7)));
    // sum/sumsq: zero the pad slots
    float z1 = 1 < rem ? x1 : 0.f;
    float z2 = 2 < rem ? x2 : 0.f;
    float z3 = 3 < rem ? x3 : 0.f;
    float z4 = 4 < rem ? x4 : 0.f;
    float z5 = 5 < rem ? x5 : 0.f;
    float z6 = 6 < rem ? x6 : 0.f;
    float z7 = 7 < rem ? x7 : 0.f;
    sA += x0; sB += z1; sC += z2; sD += z3;
    sA += z4; sB += z5; sC += z6; sD += z7;
    qA = fmaf(x0, x0, qA); qB = fmaf(z1, z1, qB);
    qC = fmaf(z2, z2, qC); qD = fmaf(z3, z3, qD);
    qA = fmaf(z4, z4, qA); qB = fmaf(z5, z5, qB);
    qC = fmaf(z6, z6, qC); qD = fmaf(z7, z7, qD);
  }
  float sx = (sA + sB) + (sC + sD);
  float qx = (qA + qB) + (qC + qD);
  float mxx = fmaxf(mx0, mx1), mnx = fminf(mn0, mn1);

  int deg = s1 - s0;
  float inv = 1.0f / fmaxf((float)deg, 1.0f);
  bool has = deg > 0;
  float m_s = sx * inv, ms_s = qx * inv;
  float sd_s = sqrtf(fmaxf(ms_s - m_s * m_s, 0.f) + 1e-5f);
  float mx_s = has ? mxx : 0.f, mn_s = has ? mnx : 0.f;

  unsigned short* bh = agg_h + (size_t)n * KEFF;
  unsigned short* bl = agg_l + (size_t)n * KEFF;
#define W2(off, val) { float _v = (val); unsigned short _h = f2bf_rne(_v); \
                       bh[(off) + lane] = _h; bl[(off) + lane] = f2bf_rne(_v - bf2f(_h)); }
  W2(64,  m_s); W2(192, mn_s); W2(320, mx_s); W2(448, sd_s);
#undef W2
}

// ===================== MFMA GEMM v6b: pipelined LDS-A, direct swizzled B ===
// Measured-best structure (BK32/BM64, R4). New: the x_dst K-chunks (k<64)
// are read straight from x (fp32) and hi/lo-split in-register during the
// prefetch slot, masked by deg>0 -- agg_x no longer materializes them.

__global__ __launch_bounds__(256, 3) void gemm_kernel(
    const float* __restrict__ x, const int* __restrict__ cnt,
    const unsigned short* __restrict__ Ah, const unsigned short* __restrict__ Al,
    const unsigned short* __restrict__ Wh, const unsigned short* __restrict__ Wl,
    const float* __restrict__ beff, const float* __restrict__ bias,
    const float* __restrict__ log_deg, const float* __restrict__ avg_ptr,
    float* __restrict__ h, double* __restrict__ bnacc)
{
  __shared__ __align__(16) short AsH[64 * 40], AsL[64 * 40];
  int tid = threadIdx.x;
  int lane = tid & 63, w = tid >> 6;
  int quad = lane >> 4, l15 = lane & 15;
  int n0 = blockIdx.x * 64;

  int arow = tid >> 2, ac = tid & 3;
  int an = n0 + arow; if (an >= N_NODES) an = N_NODES - 1;
  const float* gx = x + (size_t)an * 64 + ac * 8;
  float xm = (cnt[an] > 0) ? 1.f : 0.f;   // x_dst folding: has ? x : 0
  const unsigned short* gah = Ah + (size_t)an * KEFF + ac * 8;
  const unsigned short* gal = Al + (size_t)an * KEFF + ac * 8;

  // B colgroup base pointers: cg = s*4 + w
  const unsigned short* pbh[3];
  const unsigned short* pbl[3];
#pragma unroll
  for (int s = 0; s < 3; s++) {
    size_t cb = (size_t)(s * 4 + w) * 72 * 128 + l15 * 8;
    pbh[s] = Wh + cb;
    pbl[s] = Wl + cb;
  }

  f32x4 acc[4][3] = {};

  auto packx = [&](int k0, float4& rh, float4& rl) {
    float4 a = *(const float4*)(gx + k0);
    float4 b = *(const float4*)(gx + k0 + 4);
    u32 h0, l0, h1, l1, h2, l2, h3, l3;
    split2(a.x * xm, a.y * xm, h0, l0);
    split2(a.z * xm, a.w * xm, h1, l1);
    split2(b.x * xm, b.y * xm, h2, l2);
    split2(b.z * xm, b.w * xm, h3, l3);
    u32x4 th; th.x = h0; th.y = h1; th.z = h2; th.w = h3;
    u32x4 tl; tl.x = l0; tl.y = l1; tl.z = l2; tl.w = l3;
    rh = __builtin_bit_cast(float4, th);
    rl = __builtin_bit_cast(float4, tl);
  };

  float4 rh, rl;
  packx(0, rh, rl);

  for (int k0 = 0; k0 < KEFF; k0 += 32) {
    // B frags for this chunk (independent of LDS state)
    int koff = ((k0 >> 3) + quad) * 128;
    bf16x8 bhf[3], blf[3];
#pragma unroll
    for (int s = 0; s < 3; s++) {
      bhf[s] = *(const bf16x8*)(pbh[s] + koff);
      blf[s] = *(const bf16x8*)(pbl[s] + koff);
    }
    // publish current A chunk
    *(float4*)(AsH + arow * 40 + ac * 8) = rh;
    *(float4*)(AsL + arow * 40 + ac * 8) = rl;
    // prefetch next A chunk (consumed after the next barrier pair)
    if (k0 + 32 < KEFF) {
      if (k0 == 0) {
        packx(32, rh, rl);            // second x_dst chunk
      } else {
        rh = *(const float4*)(gah + k0 + 32);
        rl = *(const float4*)(gal + k0 + 32);
      }
    }
    __syncthreads();

#pragma unroll
    for (int i = 0; i < 4; i++) {
      int row = i * 16 + l15;
      bf16x8 ah = *(const bf16x8*)(AsH + row * 40 + quad * 8);
      bf16x8 al = *(const bf16x8*)(AsL + row * 40 + quad * 8);
#pragma unroll
      for (int s = 0; s < 3; s++) {
        acc[i][s] = __builtin_amdgcn_mfma_f32_16x16x32_bf16(ah, bhf[s], acc[i][s], 0, 0, 0);
        acc[i][s] = __builtin_amdgcn_mfma_f32_16x16x32_bf16(al, bhf[s], acc[i][s], 0, 0, 0);
        acc[i][s] = __builtin_amdgcn_mfma_f32_16x16x32_bf16(ah, blf[s], acc[i][s], 0, 0, 0);
      }
    }
    __syncthreads();
  }

  float avg = *avg_ptr;
  int col = w * 16 + l15;
  float be0 = beff[col], be1 = beff[64 + col], be2 = beff[128 + col];
  float bi = bias[col];
  float ss = 0.f, sq = 0.f;
#pragma unroll
  for (int i = 0; i < 4; i++) {
#pragma unroll
    for (int r = 0; r < 4; r++) {
      int n = n0 + i * 16 + quad * 4 + r;
      if (n < N_NODES) {
        float ld = log_deg[n];
        float amp = ld / avg, att = avg / ld;
        float v = (acc[i][0][r] + be0) + amp * (acc[i][1][r] + be1)
                + att * (acc[i][2][r] + be2) + bi;
        h[(size_t)n * 64 + col] = v;
        ss += v; sq = fmaf(v, v, sq);
      }
    }
  }
  // reduce over quads (same col every 16 lanes)
  ss += __shfl_xor(ss, 16, 64); ss += __shfl_xor(ss, 32, 64);
  sq += __shfl_xor(sq, 16, 64); sq += __shfl_xor(sq, 32, 64);
  if (quad == 0) {
    atomicAdd(&bnacc[col], (double)ss);
    atomicAdd(&bnacc[64 + col], (double)sq);
  }
}

// ===================== fused BN finalize + apply =====================

__global__ __launch_bounds__(256) void apply_kernel(
    const float* __restrict__ h, const double* __restrict__ acc,
    const float* __restrict__ g, const float* __restrict__ bnb,
    float* __restrict__ x)
{
  __shared__ float smu[64], ssc[64];
  int tid = threadIdx.x;
  if (tid < 64) {
    double mu = acc[tid] / (double)N_NODES;
    double var = acc[64 + tid] / (double)N_NODES - mu * mu;
    double rstd = 1.0 / sqrt(var + 1e-5);
    smu[tid] = (float)mu;
    ssc[tid] = (float)(rstd * (double)g[tid]);
  }
  __syncthreads();
  int i4 = blockIdx.x * 256 + tid;   // float4 index, exact grid
  const float4* h4 = (const float4*)h;
  float4* x4 = (float4*)x;
  int c4 = (i4 & 15) * 4;
  float4 hv = h4[i4], xv = x4[i4];
  float4 bb = ((const float4*)bnb)[i4 & 15];
  float4 r;
  r.x = fmaxf((hv.x - smu[c4])     * ssc[c4]     + bb.x, 0.f) + xv.x;
  r.y = fmaxf((hv.y - smu[c4 + 1]) * ssc[c4 + 1] + bb.y, 0.f) + xv.y;
  r.z = fmaxf((hv.z - smu[c4 + 2]) * ssc[c4 + 2] + bb.z, 0.f) + xv.z;
  r.w = fmaxf((hv.w - smu[c4 + 3]) * ssc[c4 + 3] + bb.w, 0.f) + xv.w;
  x4[i4] = r;
}

// ===================== pooling + head =====================

__global__ __launch_bounds__(256) void pool_kernel(
    const float* __restrict__ x, const int* __restrict__ batch,
    float* __restrict__ gsum)
{
  int tid = threadIdx.x;
  int j = tid & 63, ri = tid >> 6;
  float acc = 0.f; int cur = -1;
  for (int k = 0; k < 16; k++) {
    int n = blockIdx.x * 64 + k * 4 + ri;
    if (n < N_NODES) {
      int b = batch[n];
      if (b != cur) {
        if (cur >= 0) atomicAdd(&gsum[cur * 64 + j], acc);
        cur = b; acc = 0.f;
      }
      acc += x[(size_t)n * 64 + j];
    }
  }
  if (cur >= 0) atomicAdd(&gsum[cur * 64 + j], acc);
}

// fc head v2: one block per graph (64 blocks x 64 threads). Weights staged
// into LDS with coalesced lane-varying loads; layer1 split 2 threads/output,
// layer2 4 threads/output, layer3 1 thread/output.
__global__ __launch_bounds__(64) void fc_kernel(
    const float* __restrict__ gsum, const int* __restrict__ gcnt,
    const float* __restrict__ w1, const float* __restrict__ b1,
    const float* __restrict__ w2, const float* __restrict__ b2,
    const float* __restrict__ w3, const float* __restrict__ b3,
    float* __restrict__ out)
{
  __shared__ float w1s[64 * 32], w2s[32 * 16], w3s[16 * 10];
  __shared__ float b1s[32], b2s[16], b3s[10];
  __shared__ float gvs[64], a1s[32], a2s[16];
  int g = blockIdx.x, tid = threadIdx.x;

#pragma unroll
  for (int i = 0; i < 32; i++) w1s[tid + 64 * i] = w1[tid + 64 * i];
#pragma unroll
  for (int i = 0; i < 8; i++)  w2s[tid + 64 * i] = w2[tid + 64 * i];
  { int i2 = tid; if (i2 < 160) w3s[i2] = w3[i2];
    i2 = tid + 64; if (i2 < 160) w3s[i2] = w3[i2];
    i2 = tid + 128; if (i2 < 160) w3s[i2] = w3[i2]; }
  if (tid < 32) b1s[tid] = b1[tid];
  if (tid < 16) b2s[tid] = b2[tid];
  if (tid < 10) b3s[tid] = b3[tid];
  float cnt = fmaxf((float)gcnt[g], 1.0f);
  gvs[tid] = gsum[g * 64 + tid] / cnt;
  __syncthreads();

  // layer 1: 64->32, 2 threads per output (j-halves), combine via shfl
  {
    int o = tid & 31, half = tid >> 5;
    float s = 0.f;
#pragma unroll
    for (int j = 0; j < 32; j++)
      s = fmaf(gvs[half * 32 + j], w1s[(half * 32 + j) * 32 + o], s);
    s += __shfl_xor(s, 32, 64);
    if (half == 0) a1s[o] = fmaxf(s + b1s[o], 0.f);
  }
  __syncthreads();

  // layer 2: 32->16, 4 threads per output (j-eighths)
  {
    int o = tid & 15, part = tid >> 4;
    float s = 0.f;
#pragma unroll
    for (int j = 0; j < 8; j++)
      s = fmaf(a1s[part * 8 + j], w2s[(part * 8 + j) * 16 + o], s);
    s += __shfl_xor(s, 16, 64);
    s += __shfl_xor(s, 32, 64);
    if (part == 0) a2s[o] = fmaxf(s + b2s[o], 0.f);
  }
  __syncthreads();

  // layer 3: 16->10, 1 thread per output
  if (tid < 10) {
    float s = b3s[tid];
#pragma unroll
    for (int j = 0; j < 16; j++) s = fmaf(a2s[j], w3s[j * 10 + tid], s);
    out[g * 10 + tid] = s;
  }
}

// ===================== launch =====================

extern "C" void kernel_launch(void* const* d_in, const int* in_sizes, int n_in,
                              void* d_out, int out_size, void* d_ws, size_t ws_size,
                              hipStream_t stream)
{
  (void)in_sizes; (void)n_in; (void)out_size; (void)ws_size;
  const float* xin    = (const float*)d_in[0];
  const int*   ei     = (const int*)d_in[1];
  const int*   batch  = (const int*)d_in[2];
  const float* eattr  = (const float*)d_in[3];
  const float* node_w = (const float*)d_in[4];
  const float* node_b = (const float*)d_in[5];
  const float* edge_w = (const float*)d_in[6];
  const float* edge_b = (const float*)d_in[7];
  const float* conv_w = (const float*)d_in[8];
  const float* conv_b = (const float*)d_in[9];
  const float* bn_g   = (const float*)d_in[10];
  const float* bn_b   = (const float*)d_in[11];
  const float* fc1_w  = (const float*)d_in[12];
  const float* fc1_b  = (const float*)d_in[13];
  const float* fc2_w  = (const float*)d_in[14];
  const float* fc2_b  = (const float*)d_in[15];
  const float* fc3_w  = (const float*)d_in[16];
  const float* fc3_b  = (const float*)d_in[17];
  float* out = (float*)d_out;
  const int* srcp = ei;
  const int* dstp = ei + N_EDGES;

  char* p = (char*)d_ws;
  auto alloc = [&](size_t b) { char* r = p; p += (b + 255) & ~(size_t)255; return (void*)r; };
  float*  x       = (float*)alloc((size_t)N_NODES * 64 * 4);
  float*  h       = (float*)alloc((size_t)N_NODES * 64 * 4);
  unsigned short* agg_h = (unsigned short*)alloc((size_t)N_NODES * KEFF * 2);
  unsigned short* agg_l = (unsigned short*)alloc((size_t)N_NODES * KEFF * 2);
  unsigned short* wh    = (unsigned short*)alloc((size_t)3 * 12 * 72 * 128 * 2);
  unsigned short* wl    = (unsigned short*)alloc((size_t)3 * 12 * 72 * 128 * 2);
  int2*   edata   = (int2*)alloc((size_t)N_EDGES * 8);
  int*    rank    = (int*)alloc((size_t)N_EDGES * 4);
  float*  beff    = (float*)alloc((size_t)3 * 3 * 64 * 4);
  int*    row_ptr = (int*)alloc((N_NODES + 1) * 4);
  int*    cnt     = (int*)alloc((size_t)N_NODES * 4);
  float*  log_deg = (float*)alloc((size_t)N_NODES * 4);
  int*    bsum    = (int*)alloc(256 * 4);
  int*    boff    = (int*)alloc(256 * 4);
  double* avgacc  = (double*)alloc(256);
  float*  avgf    = (float*)alloc(256);
  double* bnacc   = (double*)alloc(3 * 128 * 8);
  float*  gsum    = (float*)alloc((size_t)NGRAPH * 64 * 4);
  int*    gcnt    = (int*)alloc((size_t)NGRAPH * 4);
  unsigned short* ewh = (unsigned short*)alloc(1024 * 2);
  unsigned short* ewl = (unsigned short*)alloc(1024 * 2);

  zero_kernel<<<213, 256, 0, stream>>>(cnt, gsum, bnacc, avgacc);
  node_enc_kernel<<<12500, 256, 0, stream>>>(xin, node_w, node_b, x);
  count_kernel<<<3125, 256, 0, stream>>>(dstp, cnt, rank);
  scan_deg_kernel<<<196, 256, 0, stream>>>(cnt, bsum, log_deg, avgacc);
  scan_b_kernel<<<1, 256, 0, stream>>>(bsum, boff);
  scan_c_kernel<<<196, 256, 0, stream>>>(cnt, boff, row_ptr);
  fill_kernel<<<3125, 256, 0, stream>>>(srcp, dstp, rank, row_ptr, edata);
  avg_gb_kernel<<<1, 64, 0, stream>>>(avgacc, avgf, batch, gcnt);
  prep_kernel<<<1298, 256, 0, stream>>>(conv_w, edge_w, wh, wl, beff, ewh, ewl);

  agg_e_kernel<<<AGG_E_BLOCKS, 256, 0, stream>>>(eattr, ewh, ewl, edge_b,
                                                 row_ptr, edata, agg_h, agg_l);

  for (int l = 0; l < 3; l++) {
    agg_x_kernel<<<12500, 256, 0, stream>>>(x, edata, row_ptr, agg_h, agg_l);
    gemm_kernel<<<782, 256, 0, stream>>>(x, cnt, agg_h, agg_l,
                                         wh + (size_t)l * 12 * 72 * 128,
                                         wl + (size_t)l * 12 * 72 * 128,
                                         beff + l * 192, conv_b + l * 64,
                                         log_deg, avgf, h, bnacc + l * 128);
    apply_kernel<<<3125, 256, 0, stream>>>(h, bnacc + l * 128, bn_g + l * 64,
                                           bn_b + l * 64, x);
  }

  pool_kernel<<<782, 256, 0, stream>>>(x, batch, gsum);
  fc_kernel<<<NGRAPH, 64, 0, stream>>>(gsum, gcnt, fc1_w, fc1_b, fc2_w, fc2_b,
                                       fc3_w, fc3_b, out);
}

// Round 12
// 582.872 us; speedup vs baseline: 1.0634x; 1.0634x over previous
//
#include <hip/hip_runtime.h>
#include <math.h>

#define N_NODES 50000
#define N_EDGES 800000
#define NGRAPH  64
#define KEFF    576   // compressed agg width (768->576 via x_dst folding)

typedef short bf16x8 __attribute__((ext_vector_type(8)));
typedef float f32x4  __attribute__((ext_vector_type(4)));
typedef float f32x16 __attribute__((ext_vector_type(16)));
typedef unsigned int u32;
typedef unsigned int u32x4 __attribute__((ext_vector_type(4)));

__device__ inline unsigned short f2bf_rne(float f) {
  unsigned u = __float_as_uint(f);
  unsigned r = u + 0x7FFFu + ((u >> 16) & 1u);
  return (unsigned short)(r >> 16);
}
__device__ inline float bf2f(unsigned short h) {
  return __uint_as_float(((unsigned)h) << 16);
}

// packed bf16 convert (RNE): dst.lo16 = bf16(a), dst.hi16 = bf16(b)
__device__ inline u32 cvtpk_bf16(float a, float b) {
  u32 r;
  asm("v_cvt_pk_bf16_f32 %0, %1, %2" : "=v"(r) : "v"(a), "v"(b));
  return r;
}

// hi/lo split of a float pair into packed bf16 words.
// lo = v - float(hi) is exact in fp32 (<=17 significant bits).
__device__ inline void split2(float a, float b, u32& ph, u32& pl) {
  ph = cvtpk_bf16(a, b);
  float ha = __uint_as_float(ph << 16);
  float hb = __uint_as_float(ph & 0xFFFF0000u);
  pl = cvtpk_bf16(a - ha, b - hb);
}

__device__ inline bf16x8 pack_bf(u32 w0, u32 w1, u32 w2, u32 w3) {
  u32x4 t;
  t.x = w0; t.y = w1; t.z = w2; t.w = w3;
  return __builtin_bit_cast(bf16x8, t);
}

// ===================== setup kernels =====================

// one kernel zeroes everything (replaces 4 memset dispatches)
__global__ __launch_bounds__(256) void zero_kernel(
    int* __restrict__ cnt, float* __restrict__ gsum,
    double* __restrict__ bnacc, double* __restrict__ avgacc)
{
  int i = blockIdx.x * 256 + threadIdx.x;   // grid 213 -> 54528
  if (i < N_NODES) { cnt[i] = 0; return; }
  int j = i - N_NODES;
  if (j < NGRAPH * 64) { gsum[j] = 0.f; return; }
  int k = j - NGRAPH * 64;
  if (k < 3 * 128) { bnacc[k] = 0.0; return; }
  if (k == 3 * 128) *avgacc = 0.0;
}

__global__ __launch_bounds__(256) void node_enc_kernel(
    const float* __restrict__ xin, const float* __restrict__ nw,
    const float* __restrict__ nb, float* __restrict__ x)
{
  __shared__ float xs[256];
  int tid = threadIdx.x;
  int base = blockIdx.x * 256;          // 4 nodes per block
  xs[tid] = xin[base + tid];
  __syncthreads();
  int r = tid >> 6, j = tid & 63;
  float acc = nb[j];
#pragma unroll
  for (int t = 0; t < 64; t++) acc = fmaf(xs[r * 64 + t], nw[t * 64 + j], acc);
  x[base + tid] = acc;
}

// count + within-node rank: the same atomic that counts gives each edge its
// slot; fill then needs NO atomic (rank written coalesced, 3.2MB).
__global__ void count_kernel(const int* __restrict__ dst, int* __restrict__ cnt,
                             int* __restrict__ rank)
{
  int e = blockIdx.x * 256 + threadIdx.x;   // grid exactly covers E
  rank[e] = atomicAdd(&cnt[dst[e]], 1);
}

// merged scan_a + deg_log: both read cnt with the same grid (196 blocks)
__global__ __launch_bounds__(256) void scan_deg_kernel(
    const int* __restrict__ cnt, int* __restrict__ bsum,
    float* __restrict__ log_deg, double* __restrict__ avgacc)
{
  __shared__ int s[256];
  __shared__ double sb[256];
  int tid = threadIdx.x;
  int i = blockIdx.x * 256 + tid;
  int v = (i < N_NODES) ? cnt[i] : 0;
  s[tid] = v;
  double c = 0.0;
  if (i < N_NODES) {
    int dc = v > 0 ? v : 1;
    log_deg[i] = logf((float)dc + 1.0f);         // log(degc + 1)
    c = (double)logf((float)v + 1.0f);           // avg uses raw deg
  }
  sb[tid] = c;
  __syncthreads();
  for (int off = 128; off > 0; off >>= 1) {
    if (tid < off) { s[tid] += s[tid + off]; sb[tid] += sb[tid + off]; }
    __syncthreads();
  }
  if (tid == 0) { bsum[blockIdx.x] = s[0]; atomicAdd(avgacc, sb[0]); }
}

__global__ __launch_bounds__(256) void scan_b_kernel(
    const int* __restrict__ bsum, int* __restrict__ boff)
{
  __shared__ int s[256];
  int tid = threadIdx.x;
  int v = (tid < 196) ? bsum[tid] : 0;
  s[tid] = v;
  __syncthreads();
  for (int off = 1; off < 256; off <<= 1) {
    int t = (tid >= off) ? s[tid - off] : 0;
    __syncthreads();
    s[tid] += t;
    __syncthreads();
  }
  boff[tid] = s[tid] - v;   // exclusive prefix of block sums
}

__global__ __launch_bounds__(256) void scan_c_kernel(
    const int* __restrict__ cnt, const int* __restrict__ boff,
    int* __restrict__ row_ptr)
{
  __shared__ int s[256];
  int tid = threadIdx.x;
  int i = blockIdx.x * 256 + tid;
  int v = (i < N_NODES) ? cnt[i] : 0;
  s[tid] = v;
  __syncthreads();
  for (int off = 1; off < 256; off <<= 1) {
    int t = (tid >= off) ? s[tid - off] : 0;
    __syncthreads();
    s[tid] += t;
    __syncthreads();
  }
  int incl = s[tid];
  int base = boff[blockIdx.x];
  if (i < N_NODES) row_ptr[i] = base + incl - v;
  if (i == N_NODES - 1) row_ptr[N_NODES] = base + incl;
}

// CSR fill, atomic-free: pos = row_ptr[dst] + rank. Single 8B scattered
// store per edge (src,eid packed) -> half the partial-line merge traffic of
// the old two-array version (WRITE_SIZE was 83MB for 6.4MB payload).
__global__ void fill_kernel(const int* __restrict__ src, const int* __restrict__ dst,
                            const int* __restrict__ rank, const int* __restrict__ row_ptr,
                            int2* __restrict__ edata)
{
  int e = blockIdx.x * 256 + threadIdx.x;
  int d = dst[e];
  int pos = row_ptr[d] + rank[e];
  edata[pos] = make_int2(src[e], e);
}

// fused: avg finalize + graph bounds (binary search on sorted batch)
__global__ void avg_gb_kernel(const double* __restrict__ avgacc,
                              float* __restrict__ avgf,
                              const int* __restrict__ batch,
                              int* __restrict__ gcnt)
{
  __shared__ int sb[65];
  int g = threadIdx.x;  // 64 threads
  int lo = 0, hi = N_NODES;
  while (lo < hi) { int mid = (lo + hi) >> 1; if (batch[mid] < g) lo = mid + 1; else hi = mid; }
  sb[g] = lo;
  if (g == 0) { sb[64] = N_NODES; *avgf = (float)(*avgacc / (double)N_NODES); }
  __syncthreads();
  gcnt[g] = sb[g + 1] - sb[g];
}

// ===================== weight prep: fold + bf16 hi/lo, MFMA-swizzled ========
// Separate kernels (R11's merged version serialized on bprep's single
// straggler block: 82us at 1.9% occupancy). B layout: [l][cg=c/16][kc=k/8]
// [c15=c%16][ko=k%8] -> B-fragment loads are lane-contiguous 1KB wave reads.

__global__ __launch_bounds__(256) void wprep_kernel(
    const float* __restrict__ conv_w, unsigned short* __restrict__ wh,
    unsigned short* __restrict__ wl)
{
  int idx = blockIdx.x * 256 + threadIdx.x;   // 3*192*576 = 331776 = 1296*256
  int k = idx % 576;
  int c = (idx / 576) % 192;
  int l = idx / (576 * 192);
  int s = c >> 6, j = c & 63;
  const float* CW = conv_w + (size_t)l * 2304 * 64;
  float v;
  if (k < 64) {
    int base = s * 768 + k;
    v = CW[base * 64 + j] + CW[(base + 192) * 64 + j] + CW[(base + 384) * 64 + j];
  } else {
    const int srcseg[8] = {1, 2, 4, 5, 7, 8, 10, 11};
    int q = (k >> 6) - 1;
    int t = k & 63;
    v = CW[(s * 768 + srcseg[q] * 64 + t) * 64 + j];
  }
  unsigned short hh = f2bf_rne(v);
  size_t o = (((size_t)l * 12 + (c >> 4)) * 72 + (k >> 3)) * 128 + (c & 15) * 8 + (k & 7);
  wh[o] = hh;
  wl[o] = f2bf_rne(v - bf2f(hh));
}

__global__ void bprep_kernel(const float* __restrict__ conv_w, float* __restrict__ beff)
{
  int l = blockIdx.x;                 // 3 blocks x 192 threads
  int s = threadIdx.x >> 6, j = threadIdx.x & 63;
  const float* CW = conv_w + (size_t)l * 2304 * 64 + (size_t)(s * 768 + 576) * 64;
  float sum = 0.f;
#pragma unroll
  for (int t = 0; t < 64; t++) sum += CW[t * 64 + j];
  beff[(l * 3 + s) * 64 + j] = sum * 0.0031622776601683794f;   // sqrt(1e-5)
}

// edge_w hi/lo MFMA B-fragments for the 32x32x16 shape, precomputed once
// (2 x 2KB, L2-resident). Consumer lane l (l31=l&31, hf=l>>5) reads element
// j of colgroup cb at [(hf*32+l31)*16 + cb*8 + j] = W[(hf*8+j)*64 + cb*32+l31].
__global__ __launch_bounds__(256) void ewprep_kernel(
    const float* __restrict__ edge_w, unsigned short* __restrict__ ewh,
    unsigned short* __restrict__ ewl)
{
  int tid = threadIdx.x;
#pragma unroll
  for (int it = 0; it < 4; it++) {
    int idx = tid + 256 * it;        // 1024 total
    int j = idx & 7, cb = (idx >> 3) & 1, l31 = (idx >> 4) & 31, hf = idx >> 9;
    float v = edge_w[(hf * 8 + j) * 64 + cb * 32 + l31];
    unsigned short h = f2bf_rne(v);
    ewh[idx] = h;
    ewl[idx] = f2bf_rne(v - bf2f(h));
  }
}

// ===================== e-segment aggregation (layer-invariant, once) ========
// 32x32x16 MFMA edge-encoder: A = 32 edges x 16 attrs (K=16 = EA_DIM, no
// stacking), each lane loads a distinct (edge, attr-half) -> no gather
// redundancy. 3 passes (hi*Wh, lo*Wh, hi*Wl) x 2 colgroups = 6 MFMA per 32
// edges. Unified masked accumulate; clamped dup ids keep min/max safe.
// Two consecutive nodes per wave step for 2x memory-level parallelism.

#define AGG_E_BLOCKS 2048
#define AGG_E_WAVES  (AGG_E_BLOCKS * 4)

__global__ __launch_bounds__(256) void agg_e_kernel(
    const float* __restrict__ eattr,
    const unsigned short* __restrict__ ewh, const unsigned short* __restrict__ ewl,
    const float* __restrict__ edge_b, const int* __restrict__ row_ptr,
    const int2* __restrict__ edata,
    unsigned short* __restrict__ agg_h, unsigned short* __restrict__ agg_l)
{
  int lane = threadIdx.x & 63;
  int l31 = lane & 31, hf = lane >> 5;
  float eb = edge_b[lane];

  int fbase = (hf * 32 + l31) * 16;
  bf16x8 wbh[2], wbl[2];
#pragma unroll
  for (int cb = 0; cb < 2; cb++) {
    wbh[cb] = *(const bf16x8*)(ewh + fbase + cb * 8);
    wbl[cb] = *(const bf16x8*)(ewl + fbase + cb * 8);
  }

  const f32x16 zero = {};
  int wid = __builtin_amdgcn_readfirstlane(blockIdx.x * 4 + (threadIdx.x >> 6));

  auto process = [&](int n, int s0, int s1, float4 d0, float4 d1) {
    int deg = s1 - s0;
    float se[2] = {0.f, 0.f}, sq[2] = {0.f, 0.f};
    float mx[2] = {-3.4e38f, -3.4e38f}, mn[2] = {3.4e38f, 3.4e38f};
    if (deg > 0) {
      int j = s0;
      while (true) {
        int remh = (s1 - j) - 4 * hf;   // valid row: baserow < remh
        u32 h0, l0, h1, l1, h2, l2, h3, l3;
        split2(d0.x, d0.y, h0, l0); split2(d0.z, d0.w, h1, l1);
        split2(d1.x, d1.y, h2, l2); split2(d1.z, d1.w, h3, l3);
        bf16x8 ahi = pack_bf(h0, h1, h2, h3), alo = pack_bf(l0, l1, l2, l3);
#pragma unroll
        for (int cb = 0; cb < 2; cb++) {
          f32x16 acc = __builtin_amdgcn_mfma_f32_32x32x16_bf16(ahi, wbh[cb], zero, 0, 0, 0);
          acc = __builtin_amdgcn_mfma_f32_32x32x16_bf16(alo, wbh[cb], acc, 0, 0, 0);
          acc = __builtin_amdgcn_mfma_f32_32x32x16_bf16(ahi, wbl[cb], acc, 0, 0, 0);
#pragma unroll
          for (int reg = 0; reg < 16; reg++) {
            const int baserow = (reg & 3) + 8 * (reg >> 2);
            float v = acc[reg];
            float vm = (baserow < remh) ? v : 0.f;   // mask pads for sum/sumsq
            se[cb] += vm; sq[cb] = fmaf(vm, vm, sq[cb]);
            // min/max: clamped duplicates are valid edge values -> harmless
            mx[cb] = fmaxf(mx[cb], v); mn[cb] = fminf(mn[cb], v);
          }
        }
        j += 32;
        if (j >= s1) break;
        // rare continuation (deg > 32): inline gather
        int id = edata[min(j + l31, s1 - 1)].y;
        const float4* pp = (const float4*)(eattr + (size_t)id * 16 + hf * 8);
        d0 = pp[0]; d1 = pp[1];
      }
    }
    // cross-half reduce: lane l and l^32 hold same col of their cb
#pragma unroll
    for (int cb = 0; cb < 2; cb++) {
      se[cb] += __shfl_xor(se[cb], 32, 64);
      sq[cb] += __shfl_xor(sq[cb], 32, 64);
      mx[cb] = fmaxf(mx[cb], __shfl_xor(mx[cb], 32, 64));
      mn[cb] = fminf(mn[cb], __shfl_xor(mn[cb], 32, 64));
    }
    // output col for lane = hf*32 + l31 = lane -> pick cb = hf
    float SE = hf ? se[1] : se[0];
    float SQ = hf ? sq[1] : sq[0];
    float MX = hf ? mx[1] : mx[0];
    float MN = hf ? mn[1] : mn[0];

    float inv = 1.0f / fmaxf((float)deg, 1.0f);
    bool has = deg > 0;
    float m0 = SE * inv, ms0 = SQ * inv;
    // variance is bias-invariant: E[(v+b)^2] - (E[v]+b)^2 = E[v^2] - E[v]^2
    float sd_e = sqrtf(fmaxf(ms0 - m0 * m0, 0.f) + 1e-5f);
    float m_e = has ? m0 + eb : 0.f;
    float mx_e = has ? MX + eb : 0.f;
    float mn_e = has ? MN + eb : 0.f;

    unsigned short* bh = agg_h + (size_t)n * KEFF;
    unsigned short* bl = agg_l + (size_t)n * KEFF;
#define W2(off, val) { float _v = (val); unsigned short _h = f2bf_rne(_v); \
                       bh[(off) + lane] = _h; bl[(off) + lane] = f2bf_rne(_v - bf2f(_h)); }
    W2(128, m_e); W2(256, mn_e); W2(384, mx_e); W2(512, sd_e);
#undef W2
  };

  for (int p = wid; p < N_NODES / 2; p += AGG_E_WAVES) {
    int nA = 2 * p;
    int r0 = row_ptr[nA], r1 = row_ptr[nA + 1], r2 = row_ptr[nA + 2];
    // both ids gathers back-to-back, then both data gathers back-to-back
    int idA = 0, idB = 0;
    if (r1 > r0) idA = edata[min(r0 + l31, r1 - 1)].y;
    if (r2 > r1) idB = edata[min(r1 + l31, r2 - 1)].y;
    float4 da0 = {}, da1 = {}, db0 = {}, db1 = {};
    if (r1 > r0) {
      const float4* pa = (const float4*)(eattr + (size_t)idA * 16 + hf * 8);
      da0 = pa[0]; da1 = pa[1];
    }
    if (r2 > r1) {
      const float4* pb = (const float4*)(eattr + (size_t)idB * 16 + hf * 8);
      db0 = pb[0]; db1 = pb[1];
    }
    process(nA, r0, r1, da0, da1);
    process(nA + 1, r1, r2, db0, db1);
  }
}

// ===================== per-layer x-segment aggregation =====================
// x8 unroll with MASKED single-iteration tail: remainder edges (deg%8) are
// gathered in parallel with clamped indices (min/max take the valid
// duplicate; sum/sumsq masked to 0) instead of up to 7 serial gathers.

__global__ __launch_bounds__(256) void agg_x_kernel(
    const float* __restrict__ x, const int2* __restrict__ edata,
    const int* __restrict__ row_ptr,
    unsigned short* __restrict__ agg_h, unsigned short* __restrict__ agg_l)
{
  int lane = threadIdx.x & 63;
  int n = blockIdx.x * 4 + (threadIdx.x >> 6);
  if (n >= N_NODES) return;
  float xd = x[(size_t)n * 64 + lane];
  int s0 = row_ptr[n], s1 = row_ptr[n + 1];
  float sA = 0.f, sB = 0.f, sC = 0.f, sD = 0.f;
  float qA = 0.f, qB = 0.f, qC = 0.f, qD = 0.f;
  float mx0 = -3.4e38f, mx1 = -3.4e38f, mn0 = 3.4e38f, mn1 = 3.4e38f;
  int j = s0;
  for (; j + 7 < s1; j += 8) {
    int e0 = edata[j].x,     e1 = edata[j + 1].x, e2 = edata[j + 2].x, e3 = edata[j + 3].x;
    int e4 = edata[j + 4].x, e5 = edata[j + 5].x, e6 = edata[j + 6].x, e7 = edata[j + 7].x;
    float x0 = x[(size_t)e0 * 64 + lane];
    float x1 = x[(size_t)e1 * 64 + lane];
    float x2 = x[(size_t)e2 * 64 + lane];
    float x3 = x[(size_t)e3 * 64 + lane];
    float x4 = x[(size_t)e4 * 64 + lane];
    float x5 = x[(size_t)e5 * 64 + lane];
    float x6 = x[(size_t)e6 * 64 + lane];
    float x7 = x[(size_t)e7 * 64 + lane];
    sA += x0; sB += x1; sC += x2; sD += x3;
    sA += x4; sB += x5; sC += x6; sD += x7;
    qA = fmaf(x0, x0, qA); qB = fmaf(x1, x1, qB);
    qC = fmaf(x2, x2, qC); qD = fmaf(x3, x3, qD);
    qA = fmaf(x4, x4, qA); qB = fmaf(x5, x5, qB);
    qC = fmaf(x6, x6, qC); qD = fmaf(x7, x7, qD);
    mx0 = fmaxf(mx0, fmaxf(fmaxf(x0, x1), fmaxf(x2, x3)));
    mx1 = fmaxf(mx1, fmaxf(fmaxf(x4, x5), fmaxf(x6, x7)));
    mn0 = fminf(mn0, fminf(fminf(x0, x1), fminf(x2, x3)));
    mn1 = fminf(mn1, fminf(fminf(x4, x5), fminf(x6, x7)));
  }
  if (j < s1) {                       // masked tail: 1..7 edges, 8 gathers in flight
    int last = s1 - 1;
    int rem = s1 - j;                 // wave-uniform
    int e0 = edata[j].x;
    int e1 = edata[j + 1 < s1 ? j + 1 : last].x;
    int e2 = edata[j + 2 < s1 ? j + 2 : last].x;
    int e3 = edata[j + 3 < s1 ? j + 3 : last].x;
    int e4 = edata[j + 4 < s1 ? j + 4 : last].x;
    int e5 = edata[j + 5 < s1 ? j + 5 : last].x;
    int e6 = edata[j + 6 < s1 ? j + 6 : last].x;
    int e7 = edata[j + 7 < s1 ? j + 7 : last].x;
    float x0 = x[(size_t)e0 * 64 + lane];
    float x1 = x[(size_t)e1 * 64 + lane];
    float x2 = x[(size_t)e2 * 64 + lane];
    float x3 = x[(size_t)e3 * 64 + lane];
    float x4 = x[(size_t)e4 * 64 + lane];
    float x5 = x[(size_t)e5 * 64 + lane];
    float x6 = x[(size_t)e6 * 64 + lane];
    float x7 = x[(size_t)e7 * 64 + lane];
    // min/max: clamped duplicates are valid edge values -> harmless
    mx0 = fmaxf(mx0, fmaxf(fmaxf(x0, x1), fmaxf(x2, x3)));
    mx1 = fmaxf(mx1, fmaxf(fmaxf(x4, x5), fmaxf(x6, x7)));
    mn0 = fminf(mn0, fminf(fminf(x0, x1), fminf(x2, x3)));
    mn1 = fminf(mn1, fminf(fminf(x4, x5), fminf(x6, x7)));
    // sum/sumsq: zero the pad slots
    float z1 = 1 < rem ? x1 : 0.f;
    float z2 = 2 < rem ? x2 : 0.f;
    float z3 = 3 < rem ? x3 : 0.f;
    float z4 = 4 < rem ? x4 : 0.f;
    float z5 = 5 < rem ? x5 : 0.f;
    float z6 = 6 < rem ? x6 : 0.f;
    float z7 = 7 < rem ? x7 : 0.f;
    sA += x0; sB += z1; sC += z2; sD += z3;
    sA += z4; sB += z5; sC += z6; sD += z7;
    qA = fmaf(x0, x0, qA); qB = fmaf(z1, z1, qB);
    qC = fmaf(z2, z2, qC); qD = fmaf(z3, z3, qD);
    qA = fmaf(z4, z4, qA); qB = fmaf(z5, z5, qB);
    qC = fmaf(z6, z6, qC); qD = fmaf(z7, z7, qD);
  }
  float sx = (sA + sB) + (sC + sD);
  float qx = (qA + qB) + (qC + qD);
  float mxx = fmaxf(mx0, mx1), mnx = fminf(mn0, mn1);

  int deg = s1 - s0;
  float inv = 1.0f / fmaxf((float)deg, 1.0f);
  bool has = deg > 0;
  float m_s = sx * inv, ms_s = qx * inv;
  float sd_s = sqrtf(fmaxf(ms_s - m_s * m_s, 0.f) + 1e-5f);
  float mx_s = has ? mxx : 0.f, mn_s = has ? mnx : 0.f;

  unsigned short* bh = agg_h + (size_t)n * KEFF;
  unsigned short* bl = agg_l + (size_t)n * KEFF;
#define W2(off, val) { float _v = (val); unsigned short _h = f2bf_rne(_v); \
                       bh[(off) + lane] = _h; bl[(off) + lane] = f2bf_rne(_v - bf2f(_h)); }
  W2(0,   has ? xd : 0.f);
  W2(64,  m_s); W2(192, mn_s); W2(320, mx_s); W2(448, sd_s);
#undef W2
}

// ===================== MFMA GEMM v6: pipelined LDS-A, direct swizzled B ====
// A chunk k+1 prefetched into registers before the barrier (latency hidden
// behind the MFMA section); B-frag loads issued first so the compiler's
// vmcnt for B uses leaves the A-prefetch in flight. Measured best across
// five structural variants (BK64, BM32, swizzled-global, barrier-free all
// regressed) -- grid 782 = 3.05 blocks/CU is grid-limited and every way to
// add blocks multiplies HBM traffic.

__global__ __launch_bounds__(256, 3) void gemm_kernel(
    const unsigned short* __restrict__ Ah, const unsigned short* __restrict__ Al,
    const unsigned short* __restrict__ Wh, const unsigned short* __restrict__ Wl,
    const float* __restrict__ beff, const float* __restrict__ bias,
    const float* __restrict__ log_deg, const float* __restrict__ avg_ptr,
    float* __restrict__ h, double* __restrict__ bnacc)
{
  __shared__ __align__(16) short AsH[64 * 40], AsL[64 * 40];
  int tid = threadIdx.x;
  int lane = tid & 63, w = tid >> 6;
  int quad = lane >> 4, l15 = lane & 15;
  int n0 = blockIdx.x * 64;

  int arow = tid >> 2, ac = tid & 3;
  int an = n0 + arow; if (an >= N_NODES) an = N_NODES - 1;
  const unsigned short* gah = Ah + (size_t)an * KEFF + ac * 8;
  const unsigned short* gal = Al + (size_t)an * KEFF + ac * 8;

  // B colgroup base pointers: cg = s*4 + w
  const unsigned short* pbh[3];
  const unsigned short* pbl[3];
#pragma unroll
  for (int s = 0; s < 3; s++) {
    size_t cb = (size_t)(s * 4 + w) * 72 * 128 + l15 * 8;
    pbh[s] = Wh + cb;
    pbl[s] = Wl + cb;
  }

  f32x4 acc[4][3] = {};
  float4 rh = *(const float4*)(gah);
  float4 rl = *(const float4*)(gal);

  for (int k0 = 0; k0 < KEFF; k0 += 32) {
    // B frags for this chunk (independent of LDS state)
    int koff = ((k0 >> 3) + quad) * 128;
    bf16x8 bhf[3], blf[3];
#pragma unroll
    for (int s = 0; s < 3; s++) {
      bhf[s] = *(const bf16x8*)(pbh[s] + koff);
      blf[s] = *(const bf16x8*)(pbl[s] + koff);
    }
    // publish current A chunk
    *(float4*)(AsH + arow * 40 + ac * 8) = rh;
    *(float4*)(AsL + arow * 40 + ac * 8) = rl;
    // prefetch next A chunk (consumed after the next barrier pair)
    if (k0 + 32 < KEFF) {
      rh = *(const float4*)(gah + k0 + 32);
      rl = *(const float4*)(gal + k0 + 32);
    }
    __syncthreads();

#pragma unroll
    for (int i = 0; i < 4; i++) {
      int row = i * 16 + l15;
      bf16x8 ah = *(const bf16x8*)(AsH + row * 40 + quad * 8);
      bf16x8 al = *(const bf16x8*)(AsL + row * 40 + quad * 8);
#pragma unroll
      for (int s = 0; s < 3; s++) {
        acc[i][s] = __builtin_amdgcn_mfma_f32_16x16x32_bf16(ah, bhf[s], acc[i][s], 0, 0, 0);
        acc[i][s] = __builtin_amdgcn_mfma_f32_16x16x32_bf16(al, bhf[s], acc[i][s], 0, 0, 0);
        acc[i][s] = __builtin_amdgcn_mfma_f32_16x16x32_bf16(ah, blf[s], acc[i][s], 0, 0, 0);
      }
    }
    __syncthreads();
  }

  float avg = *avg_ptr;
  int col = w * 16 + l15;
  float be0 = beff[col], be1 = beff[64 + col], be2 = beff[128 + col];
  float bi = bias[col];
  float ss = 0.f, sq = 0.f;
#pragma unroll
  for (int i = 0; i < 4; i++) {
#pragma unroll
    for (int r = 0; r < 4; r++) {
      int n = n0 + i * 16 + quad * 4 + r;
      if (n < N_NODES) {
        float ld = log_deg[n];
        float amp = ld / avg, att = avg / ld;
        float v = (acc[i][0][r] + be0) + amp * (acc[i][1][r] + be1)
                + att * (acc[i][2][r] + be2) + bi;
        h[(size_t)n * 64 + col] = v;
        ss += v; sq = fmaf(v, v, sq);
      }
    }
  }
  // reduce over quads (same col every 16 lanes)
  ss += __shfl_xor(ss, 16, 64); ss += __shfl_xor(ss, 32, 64);
  sq += __shfl_xor(sq, 16, 64); sq += __shfl_xor(sq, 32, 64);
  if (quad == 0) {
    atomicAdd(&bnacc[col], (double)ss);
    atomicAdd(&bnacc[64 + col], (double)sq);
  }
}

// ===================== fused BN finalize + apply =====================

__global__ __launch_bounds__(256) void apply_kernel(
    const float* __restrict__ h, const double* __restrict__ acc,
    const float* __restrict__ g, const float* __restrict__ bnb,
    float* __restrict__ x)
{
  __shared__ float smu[64], ssc[64];
  int tid = threadIdx.x;
  if (tid < 64) {
    double mu = acc[tid] / (double)N_NODES;
    double var = acc[64 + tid] / (double)N_NODES - mu * mu;
    double rstd = 1.0 / sqrt(var + 1e-5);
    smu[tid] = (float)mu;
    ssc[tid] = (float)(rstd * (double)g[tid]);
  }
  __syncthreads();
  int i4 = blockIdx.x * 256 + tid;   // float4 index, exact grid
  const float4* h4 = (const float4*)h;
  float4* x4 = (float4*)x;
  int c4 = (i4 & 15) * 4;
  float4 hv = h4[i4], xv = x4[i4];
  float4 bb = ((const float4*)bnb)[i4 & 15];
  float4 r;
  r.x = fmaxf((hv.x - smu[c4])     * ssc[c4]     + bb.x, 0.f) + xv.x;
  r.y = fmaxf((hv.y - smu[c4 + 1]) * ssc[c4 + 1] + bb.y, 0.f) + xv.y;
  r.z = fmaxf((hv.z - smu[c4 + 2]) * ssc[c4 + 2] + bb.z, 0.f) + xv.z;
  r.w = fmaxf((hv.w - smu[c4 + 3]) * ssc[c4 + 3] + bb.w, 0.f) + xv.w;
  x4[i4] = r;
}

// ===================== pooling + head =====================

__global__ __launch_bounds__(256) void pool_kernel(
    const float* __restrict__ x, const int* __restrict__ batch,
    float* __restrict__ gsum)
{
  int tid = threadIdx.x;
  int j = tid & 63, ri = tid >> 6;
  float acc = 0.f; int cur = -1;
  for (int k = 0; k < 16; k++) {
    int n = blockIdx.x * 64 + k * 4 + ri;
    if (n < N_NODES) {
      int b = batch[n];
      if (b != cur) {
        if (cur >= 0) atomicAdd(&gsum[cur * 64 + j], acc);
        cur = b; acc = 0.f;
      }
      acc += x[(size_t)n * 64 + j];
    }
  }
  if (cur >= 0) atomicAdd(&gsum[cur * 64 + j], acc);
}

// fc head v2: one block per graph (64 blocks x 64 threads). Weights staged
// into LDS with coalesced lane-varying loads; layer1 split 2 threads/output,
// layer2 4 threads/output, layer3 1 thread/output.
__global__ __launch_bounds__(64) void fc_kernel(
    const float* __restrict__ gsum, const int* __restrict__ gcnt,
    const float* __restrict__ w1, const float* __restrict__ b1,
    const float* __restrict__ w2, const float* __restrict__ b2,
    const float* __restrict__ w3, const float* __restrict__ b3,
    float* __restrict__ out)
{
  __shared__ float w1s[64 * 32], w2s[32 * 16], w3s[16 * 10];
  __shared__ float b1s[32], b2s[16], b3s[10];
  __shared__ float gvs[64], a1s[32], a2s[16];
  int g = blockIdx.x, tid = threadIdx.x;

#pragma unroll
  for (int i = 0; i < 32; i++) w1s[tid + 64 * i] = w1[tid + 64 * i];
#pragma unroll
  for (int i = 0; i < 8; i++)  w2s[tid + 64 * i] = w2[tid + 64 * i];
  { int i2 = tid; if (i2 < 160) w3s[i2] = w3[i2];
    i2 = tid + 64; if (i2 < 160) w3s[i2] = w3[i2];
    i2 = tid + 128; if (i2 < 160) w3s[i2] = w3[i2]; }
  if (tid < 32) b1s[tid] = b1[tid];
  if (tid < 16) b2s[tid] = b2[tid];
  if (tid < 10) b3s[tid] = b3[tid];
  float cnt = fmaxf((float)gcnt[g], 1.0f);
  gvs[tid] = gsum[g * 64 + tid] / cnt;
  __syncthreads();

  // layer 1: 64->32, 2 threads per output (j-halves), combine via shfl
  {
    int o = tid & 31, half = tid >> 5;
    float s = 0.f;
#pragma unroll
    for (int j = 0; j < 32; j++)
      s = fmaf(gvs[half * 32 + j], w1s[(half * 32 + j) * 32 + o], s);
    s += __shfl_xor(s, 32, 64);
    if (half == 0) a1s[o] = fmaxf(s + b1s[o], 0.f);
  }
  __syncthreads();

  // layer 2: 32->16, 4 threads per output (j-eighths)
  {
    int o = tid & 15, part = tid >> 4;
    float s = 0.f;
#pragma unroll
    for (int j = 0; j < 8; j++)
      s = fmaf(a1s[part * 8 + j], w2s[(part * 8 + j) * 16 + o], s);
    s += __shfl_xor(s, 16, 64);
    s += __shfl_xor(s, 32, 64);
    if (part == 0) a2s[o] = fmaxf(s + b2s[o], 0.f);
  }
  __syncthreads();

  // layer 3: 16->10, 1 thread per output
  if (tid < 10) {
    float s = b3s[tid];
#pragma unroll
    for (int j = 0; j < 16; j++) s = fmaf(a2s[j], w3s[j * 10 + tid], s);
    out[g * 10 + tid] = s;
  }
}

// ===================== launch =====================

extern "C" void kernel_launch(void* const* d_in, const int* in_sizes, int n_in,
                              void* d_out, int out_size, void* d_ws, size_t ws_size,
                              hipStream_t stream)
{
  (void)in_sizes; (void)n_in; (void)out_size; (void)ws_size;
  const float* xin    = (const float*)d_in[0];
  const int*   ei     = (const int*)d_in[1];
  const int*   batch  = (const int*)d_in[2];
  const float* eattr  = (const float*)d_in[3];
  const float* node_w = (const float*)d_in[4];
  const float* node_b = (const float*)d_in[5];
  const float* edge_w = (const float*)d_in[6];
  const float* edge_b = (const float*)d_in[7];
  const float* conv_w = (const float*)d_in[8];
  const float* conv_b = (const float*)d_in[9];
  const float* bn_g   = (const float*)d_in[10];
  const float* bn_b   = (const float*)d_in[11];
  const float* fc1_w  = (const float*)d_in[12];
  const float* fc1_b  = (const float*)d_in[13];
  const float* fc2_w  = (const float*)d_in[14];
  const float* fc2_b  = (const float*)d_in[15];
  const float* fc3_w  = (const float*)d_in[16];
  const float* fc3_b  = (const float*)d_in[17];
  float* out = (float*)d_out;
  const int* srcp = ei;
  const int* dstp = ei + N_EDGES;

  char* p = (char*)d_ws;
  auto alloc = [&](size_t b) { char* r = p; p += (b + 255) & ~(size_t)255; return (void*)r; };
  float*  x       = (float*)alloc((size_t)N_NODES * 64 * 4);
  float*  h       = (float*)alloc((size_t)N_NODES * 64 * 4);
  unsigned short* agg_h = (unsigned short*)alloc((size_t)N_NODES * KEFF * 2);
  unsigned short* agg_l = (unsigned short*)alloc((size_t)N_NODES * KEFF * 2);
  unsigned short* wh    = (unsigned short*)alloc((size_t)3 * 12 * 72 * 128 * 2);
  unsigned short* wl    = (unsigned short*)alloc((size_t)3 * 12 * 72 * 128 * 2);
  int2*   edata   = (int2*)alloc((size_t)N_EDGES * 8);
  int*    rank    = (int*)alloc((size_t)N_EDGES * 4);
  float*  beff    = (float*)alloc((size_t)3 * 3 * 64 * 4);
  int*    row_ptr = (int*)alloc((N_NODES + 1) * 4);
  int*    cnt     = (int*)alloc((size_t)N_NODES * 4);
  float*  log_deg = (float*)alloc((size_t)N_NODES * 4);
  int*    bsum    = (int*)alloc(256 * 4);
  int*    boff    = (int*)alloc(256 * 4);
  double* avgacc  = (double*)alloc(256);
  float*  avgf    = (float*)alloc(256);
  double* bnacc   = (double*)alloc(3 * 128 * 8);
  float*  gsum    = (float*)alloc((size_t)NGRAPH * 64 * 4);
  int*    gcnt    = (int*)alloc((size_t)NGRAPH * 4);
  unsigned short* ewh = (unsigned short*)alloc(1024 * 2);
  unsigned short* ewl = (unsigned short*)alloc(1024 * 2);

  zero_kernel<<<213, 256, 0, stream>>>(cnt, gsum, bnacc, avgacc);
  node_enc_kernel<<<12500, 256, 0, stream>>>(xin, node_w, node_b, x);
  count_kernel<<<3125, 256, 0, stream>>>(dstp, cnt, rank);
  scan_deg_kernel<<<196, 256, 0, stream>>>(cnt, bsum, log_deg, avgacc);
  scan_b_kernel<<<1, 256, 0, stream>>>(bsum, boff);
  scan_c_kernel<<<196, 256, 0, stream>>>(cnt, boff, row_ptr);
  fill_kernel<<<3125, 256, 0, stream>>>(srcp, dstp, rank, row_ptr, edata);
  avg_gb_kernel<<<1, 64, 0, stream>>>(avgacc, avgf, batch, gcnt);
  wprep_kernel<<<1296, 256, 0, stream>>>(conv_w, wh, wl);
  bprep_kernel<<<3, 192, 0, stream>>>(conv_w, beff);
  ewprep_kernel<<<1, 256, 0, stream>>>(edge_w, ewh, ewl);

  agg_e_kernel<<<AGG_E_BLOCKS, 256, 0, stream>>>(eattr, ewh, ewl, edge_b,
                                                 row_ptr, edata, agg_h, agg_l);

  for (int l = 0; l < 3; l++) {
    agg_x_kernel<<<12500, 256, 0, stream>>>(x, edata, row_ptr, agg_h, agg_l);
    gemm_kernel<<<782, 256, 0, stream>>>(agg_h, agg_l,
                                         wh + (size_t)l * 12 * 72 * 128,
                                         wl + (size_t)l * 12 * 72 * 128,
                                         beff + l * 192, conv_b + l * 64,
                                         log_deg, avgf, h, bnacc + l * 128);
    apply_kernel<<<3125, 256, 0, stream>>>(h, bnacc + l * 128, bn_g + l * 64,
                                           bn_b + l * 64, x);
  }

  pool_kernel<<<782, 256, 0, stream>>>(x, batch, gsum);
  fc_kernel<<<NGRAPH, 64, 0, stream>>>(gsum, gcnt, fc1_w, fc1_b, fc2_w, fc2_b,
                                       fc3_w, fc3_b, out);
}

// Round 13
// 581.247 us; speedup vs baseline: 1.0664x; 1.0028x over previous
//
#include <hip/hip_runtime.h>
#include <math.h>

#define N_NODES 50000
#define N_EDGES 800000
#define NGRAPH  64
#define KEFF    576   // compressed agg width (768->576 via x_dst folding)

typedef short bf16x8 __attribute__((ext_vector_type(8)));
typedef float f32x4  __attribute__((ext_vector_type(4)));
typedef float f32x16 __attribute__((ext_vector_type(16)));
typedef unsigned int u32;
typedef unsigned int u32x4 __attribute__((ext_vector_type(4)));

__device__ inline unsigned short f2bf_rne(float f) {
  unsigned u = __float_as_uint(f);
  unsigned r = u + 0x7FFFu + ((u >> 16) & 1u);
  return (unsigned short)(r >> 16);
}
__device__ inline float bf2f(unsigned short h) {
  return __uint_as_float(((unsigned)h) << 16);
}

// packed bf16 convert (RNE): dst.lo16 = bf16(a), dst.hi16 = bf16(b)
__device__ inline u32 cvtpk_bf16(float a, float b) {
  u32 r;
  asm("v_cvt_pk_bf16_f32 %0, %1, %2" : "=v"(r) : "v"(a), "v"(b));
  return r;
}

// hi/lo split of a float pair into packed bf16 words.
// lo = v - float(hi) is exact in fp32 (<=17 significant bits).
__device__ inline void split2(float a, float b, u32& ph, u32& pl) {
  ph = cvtpk_bf16(a, b);
  float ha = __uint_as_float(ph << 16);
  float hb = __uint_as_float(ph & 0xFFFF0000u);
  pl = cvtpk_bf16(a - ha, b - hb);
}

__device__ inline bf16x8 pack_bf(u32 w0, u32 w1, u32 w2, u32 w3) {
  u32x4 t;
  t.x = w0; t.y = w1; t.z = w2; t.w = w3;
  return __builtin_bit_cast(bf16x8, t);
}

// LDS-only barrier: lgkmcnt(0) + s_barrier WITHOUT the compiler's implicit
// vmcnt(0) drain -- keeps the A-prefetch global load in flight across the
// barrier (the m97-structure drain was the measured stall; gemm's inter-wave
// ordering requirement is purely LDS producer/consumer).
__device__ inline void lds_barrier() {
  asm volatile("s_waitcnt lgkmcnt(0)\n\ts_barrier" ::: "memory");
}

// ===================== setup kernels =====================

// one kernel zeroes everything (replaces 4 memset dispatches)
__global__ __launch_bounds__(256) void zero_kernel(
    int* __restrict__ cnt, float* __restrict__ gsum,
    double* __restrict__ bnacc, double* __restrict__ avgacc)
{
  int i = blockIdx.x * 256 + threadIdx.x;   // grid 213 -> 54528
  if (i < N_NODES) { cnt[i] = 0; return; }
  int j = i - N_NODES;
  if (j < NGRAPH * 64) { gsum[j] = 0.f; return; }
  int k = j - NGRAPH * 64;
  if (k < 3 * 128) { bnacc[k] = 0.0; return; }
  if (k == 3 * 128) *avgacc = 0.0;
}

__global__ __launch_bounds__(256) void node_enc_kernel(
    const float* __restrict__ xin, const float* __restrict__ nw,
    const float* __restrict__ nb, float* __restrict__ x)
{
  __shared__ float xs[256];
  int tid = threadIdx.x;
  int base = blockIdx.x * 256;          // 4 nodes per block
  xs[tid] = xin[base + tid];
  __syncthreads();
  int r = tid >> 6, j = tid & 63;
  float acc = nb[j];
#pragma unroll
  for (int t = 0; t < 64; t++) acc = fmaf(xs[r * 64 + t], nw[t * 64 + j], acc);
  x[base + tid] = acc;
}

// count + within-node rank: the same atomic that counts gives each edge its
// slot; fill then needs NO atomic (rank written coalesced, 3.2MB).
__global__ void count_kernel(const int* __restrict__ dst, int* __restrict__ cnt,
                             int* __restrict__ rank)
{
  int e = blockIdx.x * 256 + threadIdx.x;   // grid exactly covers E
  rank[e] = atomicAdd(&cnt[dst[e]], 1);
}

// merged scan_a + deg_log: both read cnt with the same grid (196 blocks)
__global__ __launch_bounds__(256) void scan_deg_kernel(
    const int* __restrict__ cnt, int* __restrict__ bsum,
    float* __restrict__ log_deg, double* __restrict__ avgacc)
{
  __shared__ int s[256];
  __shared__ double sb[256];
  int tid = threadIdx.x;
  int i = blockIdx.x * 256 + tid;
  int v = (i < N_NODES) ? cnt[i] : 0;
  s[tid] = v;
  double c = 0.0;
  if (i < N_NODES) {
    int dc = v > 0 ? v : 1;
    log_deg[i] = logf((float)dc + 1.0f);         // log(degc + 1)
    c = (double)logf((float)v + 1.0f);           // avg uses raw deg
  }
  sb[tid] = c;
  __syncthreads();
  for (int off = 128; off > 0; off >>= 1) {
    if (tid < off) { s[tid] += s[tid + off]; sb[tid] += sb[tid + off]; }
    __syncthreads();
  }
  if (tid == 0) { bsum[blockIdx.x] = s[0]; atomicAdd(avgacc, sb[0]); }
}

__global__ __launch_bounds__(256) void scan_b_kernel(
    const int* __restrict__ bsum, int* __restrict__ boff)
{
  __shared__ int s[256];
  int tid = threadIdx.x;
  int v = (tid < 196) ? bsum[tid] : 0;
  s[tid] = v;
  __syncthreads();
  for (int off = 1; off < 256; off <<= 1) {
    int t = (tid >= off) ? s[tid - off] : 0;
    __syncthreads();
    s[tid] += t;
    __syncthreads();
  }
  boff[tid] = s[tid] - v;   // exclusive prefix of block sums
}

__global__ __launch_bounds__(256) void scan_c_kernel(
    const int* __restrict__ cnt, const int* __restrict__ boff,
    int* __restrict__ row_ptr)
{
  __shared__ int s[256];
  int tid = threadIdx.x;
  int i = blockIdx.x * 256 + tid;
  int v = (i < N_NODES) ? cnt[i] : 0;
  s[tid] = v;
  __syncthreads();
  for (int off = 1; off < 256; off <<= 1) {
    int t = (tid >= off) ? s[tid - off] : 0;
    __syncthreads();
    s[tid] += t;
    __syncthreads();
  }
  int incl = s[tid];
  int base = boff[blockIdx.x];
  if (i < N_NODES) row_ptr[i] = base + incl - v;
  if (i == N_NODES - 1) row_ptr[N_NODES] = base + incl;
}

// CSR fill, atomic-free: pos = row_ptr[dst] + rank. Single 8B scattered
// store per edge (src,eid packed) -> half the partial-line merge traffic of
// the old two-array version (WRITE_SIZE was 83MB for 6.4MB payload).
__global__ void fill_kernel(const int* __restrict__ src, const int* __restrict__ dst,
                            const int* __restrict__ rank, const int* __restrict__ row_ptr,
                            int2* __restrict__ edata)
{
  int e = blockIdx.x * 256 + threadIdx.x;
  int d = dst[e];
  int pos = row_ptr[d] + rank[e];
  edata[pos] = make_int2(src[e], e);
}

// fused: avg finalize + graph bounds (binary search on sorted batch)
__global__ void avg_gb_kernel(const double* __restrict__ avgacc,
                              float* __restrict__ avgf,
                              const int* __restrict__ batch,
                              int* __restrict__ gcnt)
{
  __shared__ int sb[65];
  int g = threadIdx.x;  // 64 threads
  int lo = 0, hi = N_NODES;
  while (lo < hi) { int mid = (lo + hi) >> 1; if (batch[mid] < g) lo = mid + 1; else hi = mid; }
  sb[g] = lo;
  if (g == 0) { sb[64] = N_NODES; *avgf = (float)(*avgacc / (double)N_NODES); }
  __syncthreads();
  gcnt[g] = sb[g + 1] - sb[g];
}

// ===================== weight prep: fold + bf16 hi/lo, MFMA-swizzled ========
// Separate kernels (R11's merged version serialized on bprep's single
// straggler block: 82us at 1.9% occupancy). B layout: [l][cg=c/16][kc=k/8]
// [c15=c%16][ko=k%8] -> B-fragment loads are lane-contiguous 1KB wave reads.

__global__ __launch_bounds__(256) void wprep_kernel(
    const float* __restrict__ conv_w, unsigned short* __restrict__ wh,
    unsigned short* __restrict__ wl)
{
  int idx = blockIdx.x * 256 + threadIdx.x;   // 3*192*576 = 331776 = 1296*256
  int k = idx % 576;
  int c = (idx / 576) % 192;
  int l = idx / (576 * 192);
  int s = c >> 6, j = c & 63;
  const float* CW = conv_w + (size_t)l * 2304 * 64;
  float v;
  if (k < 64) {
    int base = s * 768 + k;
    v = CW[base * 64 + j] + CW[(base + 192) * 64 + j] + CW[(base + 384) * 64 + j];
  } else {
    const int srcseg[8] = {1, 2, 4, 5, 7, 8, 10, 11};
    int q = (k >> 6) - 1;
    int t = k & 63;
    v = CW[(s * 768 + srcseg[q] * 64 + t) * 64 + j];
  }
  unsigned short hh = f2bf_rne(v);
  size_t o = (((size_t)l * 12 + (c >> 4)) * 72 + (k >> 3)) * 128 + (c & 15) * 8 + (k & 7);
  wh[o] = hh;
  wl[o] = f2bf_rne(v - bf2f(hh));
}

__global__ void bprep_kernel(const float* __restrict__ conv_w, float* __restrict__ beff)
{
  int l = blockIdx.x;                 // 3 blocks x 192 threads
  int s = threadIdx.x >> 6, j = threadIdx.x & 63;
  const float* CW = conv_w + (size_t)l * 2304 * 64 + (size_t)(s * 768 + 576) * 64;
  float sum = 0.f;
#pragma unroll
  for (int t = 0; t < 64; t++) sum += CW[t * 64 + j];
  beff[(l * 3 + s) * 64 + j] = sum * 0.0031622776601683794f;   // sqrt(1e-5)
}

// edge_w hi/lo MFMA B-fragments for the 32x32x16 shape, precomputed once
// (2 x 2KB, L2-resident). Consumer lane l (l31=l&31, hf=l>>5) reads element
// j of colgroup cb at [(hf*32+l31)*16 + cb*8 + j] = W[(hf*8+j)*64 + cb*32+l31].
__global__ __launch_bounds__(256) void ewprep_kernel(
    const float* __restrict__ edge_w, unsigned short* __restrict__ ewh,
    unsigned short* __restrict__ ewl)
{
  int tid = threadIdx.x;
#pragma unroll
  for (int it = 0; it < 4; it++) {
    int idx = tid + 256 * it;        // 1024 total
    int j = idx & 7, cb = (idx >> 3) & 1, l31 = (idx >> 4) & 31, hf = idx >> 9;
    float v = edge_w[(hf * 8 + j) * 64 + cb * 32 + l31];
    unsigned short h = f2bf_rne(v);
    ewh[idx] = h;
    ewl[idx] = f2bf_rne(v - bf2f(h));
  }
}

// ===================== e-segment aggregation (layer-invariant, once) ========
// 32x32x16 MFMA edge-encoder: A = 32 edges x 16 attrs (K=16 = EA_DIM, no
// stacking), each lane loads a distinct (edge, attr-half) -> no gather
// redundancy. 3 passes (hi*Wh, lo*Wh, hi*Wl) x 2 colgroups = 6 MFMA per 32
// edges. Unified masked accumulate; clamped dup ids keep min/max safe.
// Two consecutive nodes per wave step for 2x memory-level parallelism.

#define AGG_E_BLOCKS 2048
#define AGG_E_WAVES  (AGG_E_BLOCKS * 4)

__global__ __launch_bounds__(256) void agg_e_kernel(
    const float* __restrict__ eattr,
    const unsigned short* __restrict__ ewh, const unsigned short* __restrict__ ewl,
    const float* __restrict__ edge_b, const int* __restrict__ row_ptr,
    const int2* __restrict__ edata,
    unsigned short* __restrict__ agg_h, unsigned short* __restrict__ agg_l)
{
  int lane = threadIdx.x & 63;
  int l31 = lane & 31, hf = lane >> 5;
  float eb = edge_b[lane];

  int fbase = (hf * 32 + l31) * 16;
  bf16x8 wbh[2], wbl[2];
#pragma unroll
  for (int cb = 0; cb < 2; cb++) {
    wbh[cb] = *(const bf16x8*)(ewh + fbase + cb * 8);
    wbl[cb] = *(const bf16x8*)(ewl + fbase + cb * 8);
  }

  const f32x16 zero = {};
  int wid = __builtin_amdgcn_readfirstlane(blockIdx.x * 4 + (threadIdx.x >> 6));

  auto process = [&](int n, int s0, int s1, float4 d0, float4 d1) {
    int deg = s1 - s0;
    float se[2] = {0.f, 0.f}, sq[2] = {0.f, 0.f};
    float mx[2] = {-3.4e38f, -3.4e38f}, mn[2] = {3.4e38f, 3.4e38f};
    if (deg > 0) {
      int j = s0;
      while (true) {
        int remh = (s1 - j) - 4 * hf;   // valid row: baserow < remh
        u32 h0, l0, h1, l1, h2, l2, h3, l3;
        split2(d0.x, d0.y, h0, l0); split2(d0.z, d0.w, h1, l1);
        split2(d1.x, d1.y, h2, l2); split2(d1.z, d1.w, h3, l3);
        bf16x8 ahi = pack_bf(h0, h1, h2, h3), alo = pack_bf(l0, l1, l2, l3);
#pragma unroll
        for (int cb = 0; cb < 2; cb++) {
          f32x16 acc = __builtin_amdgcn_mfma_f32_32x32x16_bf16(ahi, wbh[cb], zero, 0, 0, 0);
          acc = __builtin_amdgcn_mfma_f32_32x32x16_bf16(alo, wbh[cb], acc, 0, 0, 0);
          acc = __builtin_amdgcn_mfma_f32_32x32x16_bf16(ahi, wbl[cb], acc, 0, 0, 0);
#pragma unroll
          for (int reg = 0; reg < 16; reg++) {
            const int baserow = (reg & 3) + 8 * (reg >> 2);
            float v = acc[reg];
            float vm = (baserow < remh) ? v : 0.f;   // mask pads for sum/sumsq
            se[cb] += vm; sq[cb] = fmaf(vm, vm, sq[cb]);
            // min/max: clamped duplicates are valid edge values -> harmless
            mx[cb] = fmaxf(mx[cb], v); mn[cb] = fminf(mn[cb], v);
          }
        }
        j += 32;
        if (j >= s1) break;
        // rare continuation (deg > 32): inline gather
        int id = edata[min(j + l31, s1 - 1)].y;
        const float4* pp = (const float4*)(eattr + (size_t)id * 16 + hf * 8);
        d0 = pp[0]; d1 = pp[1];
      }
    }
    // cross-half reduce: lane l and l^32 hold same col of their cb
#pragma unroll
    for (int cb = 0; cb < 2; cb++) {
      se[cb] += __shfl_xor(se[cb], 32, 64);
      sq[cb] += __shfl_xor(sq[cb], 32, 64);
      mx[cb] = fmaxf(mx[cb], __shfl_xor(mx[cb], 32, 64));
      mn[cb] = fminf(mn[cb], __shfl_xor(mn[cb], 32, 64));
    }
    // output col for lane = hf*32 + l31 = lane -> pick cb = hf
    float SE = hf ? se[1] : se[0];
    float SQ = hf ? sq[1] : sq[0];
    float MX = hf ? mx[1] : mx[0];
    float MN = hf ? mn[1] : mn[0];

    float inv = 1.0f / fmaxf((float)deg, 1.0f);
    bool has = deg > 0;
    float m0 = SE * inv, ms0 = SQ * inv;
    // variance is bias-invariant: E[(v+b)^2] - (E[v]+b)^2 = E[v^2] - E[v]^2
    float sd_e = sqrtf(fmaxf(ms0 - m0 * m0, 0.f) + 1e-5f);
    float m_e = has ? m0 + eb : 0.f;
    float mx_e = has ? MX + eb : 0.f;
    float mn_e = has ? MN + eb : 0.f;

    unsigned short* bh = agg_h + (size_t)n * KEFF;
    unsigned short* bl = agg_l + (size_t)n * KEFF;
#define W2(off, val) { float _v = (val); unsigned short _h = f2bf_rne(_v); \
                       bh[(off) + lane] = _h; bl[(off) + lane] = f2bf_rne(_v - bf2f(_h)); }
    W2(128, m_e); W2(256, mn_e); W2(384, mx_e); W2(512, sd_e);
#undef W2
  };

  for (int p = wid; p < N_NODES / 2; p += AGG_E_WAVES) {
    int nA = 2 * p;
    int r0 = row_ptr[nA], r1 = row_ptr[nA + 1], r2 = row_ptr[nA + 2];
    // both ids gathers back-to-back, then both data gathers back-to-back
    int idA = 0, idB = 0;
    if (r1 > r0) idA = edata[min(r0 + l31, r1 - 1)].y;
    if (r2 > r1) idB = edata[min(r1 + l31, r2 - 1)].y;
    float4 da0 = {}, da1 = {}, db0 = {}, db1 = {};
    if (r1 > r0) {
      const float4* pa = (const float4*)(eattr + (size_t)idA * 16 + hf * 8);
      da0 = pa[0]; da1 = pa[1];
    }
    if (r2 > r1) {
      const float4* pb = (const float4*)(eattr + (size_t)idB * 16 + hf * 8);
      db0 = pb[0]; db1 = pb[1];
    }
    process(nA, r0, r1, da0, da1);
    process(nA + 1, r1, r2, db0, db1);
  }
}

// ===================== per-layer x-segment aggregation =====================
// x8 unroll with MASKED single-iteration tail: remainder edges (deg%8) are
// gathered in parallel with clamped indices (min/max take the valid
// duplicate; sum/sumsq masked to 0) instead of up to 7 serial gathers.

__global__ __launch_bounds__(256) void agg_x_kernel(
    const float* __restrict__ x, const int2* __restrict__ edata,
    const int* __restrict__ row_ptr,
    unsigned short* __restrict__ agg_h, unsigned short* __restrict__ agg_l)
{
  int lane = threadIdx.x & 63;
  int n = blockIdx.x * 4 + (threadIdx.x >> 6);
  if (n >= N_NODES) return;
  float xd = x[(size_t)n * 64 + lane];
  int s0 = row_ptr[n], s1 = row_ptr[n + 1];
  float sA = 0.f, sB = 0.f, sC = 0.f, sD = 0.f;
  float qA = 0.f, qB = 0.f, qC = 0.f, qD = 0.f;
  float mx0 = -3.4e38f, mx1 = -3.4e38f, mn0 = 3.4e38f, mn1 = 3.4e38f;
  int j = s0;
  for (; j + 7 < s1; j += 8) {
    int e0 = edata[j].x,     e1 = edata[j + 1].x, e2 = edata[j + 2].x, e3 = edata[j + 3].x;
    int e4 = edata[j + 4].x, e5 = edata[j + 5].x, e6 = edata[j + 6].x, e7 = edata[j + 7].x;
    float x0 = x[(size_t)e0 * 64 + lane];
    float x1 = x[(size_t)e1 * 64 + lane];
    float x2 = x[(size_t)e2 * 64 + lane];
    float x3 = x[(size_t)e3 * 64 + lane];
    float x4 = x[(size_t)e4 * 64 + lane];
    float x5 = x[(size_t)e5 * 64 + lane];
    float x6 = x[(size_t)e6 * 64 + lane];
    float x7 = x[(size_t)e7 * 64 + lane];
    sA += x0; sB += x1; sC += x2; sD += x3;
    sA += x4; sB += x5; sC += x6; sD += x7;
    qA = fmaf(x0, x0, qA); qB = fmaf(x1, x1, qB);
    qC = fmaf(x2, x2, qC); qD = fmaf(x3, x3, qD);
    qA = fmaf(x4, x4, qA); qB = fmaf(x5, x5, qB);
    qC = fmaf(x6, x6, qC); qD = fmaf(x7, x7, qD);
    mx0 = fmaxf(mx0, fmaxf(fmaxf(x0, x1), fmaxf(x2, x3)));
    mx1 = fmaxf(mx1, fmaxf(fmaxf(x4, x5), fmaxf(x6, x7)));
    mn0 = fminf(mn0, fminf(fminf(x0, x1), fminf(x2, x3)));
    mn1 = fminf(mn1, fminf(fminf(x4, x5), fminf(x6, x7)));
  }
  if (j < s1) {                       // masked tail: 1..7 edges, 8 gathers in flight
    int last = s1 - 1;
    int rem = s1 - j;                 // wave-uniform
    int e0 = edata[j].x;
    int e1 = edata[j + 1 < s1 ? j + 1 : last].x;
    int e2 = edata[j + 2 < s1 ? j + 2 : last].x;
    int e3 = edata[j + 3 < s1 ? j + 3 : last].x;
    int e4 = edata[j + 4 < s1 ? j + 4 : last].x;
    int e5 = edata[j + 5 < s1 ? j + 5 : last].x;
    int e6 = edata[j + 6 < s1 ? j + 6 : last].x;
    int e7 = edata[j + 7 < s1 ? j + 7 : last].x;
    float x0 = x[(size_t)e0 * 64 + lane];
    float x1 = x[(size_t)e1 * 64 + lane];
    float x2 = x[(size_t)e2 * 64 + lane];
    float x3 = x[(size_t)e3 * 64 + lane];
    float x4 = x[(size_t)e4 * 64 + lane];
    float x5 = x[(size_t)e5 * 64 + lane];
    float x6 = x[(size_t)e6 * 64 + lane];
    float x7 = x[(size_t)e7 * 64 + lane];
    // min/max: clamped duplicates are valid edge values -> harmless
    mx0 = fmaxf(mx0, fmaxf(fmaxf(x0, x1), fmaxf(x2, x3)));
    mx1 = fmaxf(mx1, fmaxf(fmaxf(x4, x5), fmaxf(x6, x7)));
    mn0 = fminf(mn0, fminf(fminf(x0, x1), fminf(x2, x3)));
    mn1 = fminf(mn1, fminf(fminf(x4, x5), fminf(x6, x7)));
    // sum/sumsq: zero the pad slots
    float z1 = 1 < rem ? x1 : 0.f;
    float z2 = 2 < rem ? x2 : 0.f;
    float z3 = 3 < rem ? x3 : 0.f;
    float z4 = 4 < rem ? x4 : 0.f;
    float z5 = 5 < rem ? x5 : 0.f;
    float z6 = 6 < rem ? x6 : 0.f;
    float z7 = 7 < rem ? x7 : 0.f;
    sA += x0; sB += z1; sC += z2; sD += z3;
    sA += z4; sB += z5; sC += z6; sD += z7;
    qA = fmaf(x0, x0, qA); qB = fmaf(z1, z1, qB);
    qC = fmaf(z2, z2, qC); qD = fmaf(z3, z3, qD);
    qA = fmaf(z4, z4, qA); qB = fmaf(z5, z5, qB);
    qC = fmaf(z6, z6, qC); qD = fmaf(z7, z7, qD);
  }
  float sx = (sA + sB) + (sC + sD);
  float qx = (qA + qB) + (qC + qD);
  float mxx = fmaxf(mx0, mx1), mnx = fminf(mn0, mn1);

  int deg = s1 - s0;
  float inv = 1.0f / fmaxf((float)deg, 1.0f);
  bool has = deg > 0;
  float m_s = sx * inv, ms_s = qx * inv;
  float sd_s = sqrtf(fmaxf(ms_s - m_s * m_s, 0.f) + 1e-5f);
  float mx_s = has ? mxx : 0.f, mn_s = has ? mnx : 0.f;

  unsigned short* bh = agg_h + (size_t)n * KEFF;
  unsigned short* bl = agg_l + (size_t)n * KEFF;
#define W2(off, val) { float _v = (val); unsigned short _h = f2bf_rne(_v); \
                       bh[(off) + lane] = _h; bl[(off) + lane] = f2bf_rne(_v - bf2f(_h)); }
  W2(0,   has ? xd : 0.f);
  W2(64,  m_s); W2(192, mn_s); W2(320, mx_s); W2(448, sd_s);
#undef W2
}

// ===================== MFMA GEMM v6c: LDS-A pipeline, lgkm-only barriers ===
// Measured-best structure (BK32/BM64) with the one remaining lever: the
// compiler's implicit vmcnt(0) drain at __syncthreads is replaced by an
// LDS-only barrier (lgkmcnt(0)+s_barrier), so the A-prefetch global load
// stays in flight across the barrier. Inter-wave ordering requirement here
// is purely LDS producer/consumer -> lgkmcnt(0) suffices; the prefetch's
// consumer (next iteration's ds_write) keeps its natural vmcnt wait.

__global__ __launch_bounds__(256, 3) void gemm_kernel(
    const unsigned short* __restrict__ Ah, const unsigned short* __restrict__ Al,
    const unsigned short* __restrict__ Wh, const unsigned short* __restrict__ Wl,
    const float* __restrict__ beff, const float* __restrict__ bias,
    const float* __restrict__ log_deg, const float* __restrict__ avg_ptr,
    float* __restrict__ h, double* __restrict__ bnacc)
{
  __shared__ __align__(16) short AsH[64 * 40], AsL[64 * 40];
  int tid = threadIdx.x;
  int lane = tid & 63, w = tid >> 6;
  int quad = lane >> 4, l15 = lane & 15;
  int n0 = blockIdx.x * 64;

  int arow = tid >> 2, ac = tid & 3;
  int an = n0 + arow; if (an >= N_NODES) an = N_NODES - 1;
  const unsigned short* gah = Ah + (size_t)an * KEFF + ac * 8;
  const unsigned short* gal = Al + (size_t)an * KEFF + ac * 8;

  // B colgroup base pointers: cg = s*4 + w
  const unsigned short* pbh[3];
  const unsigned short* pbl[3];
#pragma unroll
  for (int s = 0; s < 3; s++) {
    size_t cb = (size_t)(s * 4 + w) * 72 * 128 + l15 * 8;
    pbh[s] = Wh + cb;
    pbl[s] = Wl + cb;
  }

  f32x4 acc[4][3] = {};
  float4 rh = *(const float4*)(gah);
  float4 rl = *(const float4*)(gal);

  for (int k0 = 0; k0 < KEFF; k0 += 32) {
    // B frags for this chunk (independent of LDS state)
    int koff = ((k0 >> 3) + quad) * 128;
    bf16x8 bhf[3], blf[3];
#pragma unroll
    for (int s = 0; s < 3; s++) {
      bhf[s] = *(const bf16x8*)(pbh[s] + koff);
      blf[s] = *(const bf16x8*)(pbl[s] + koff);
    }
    // publish current A chunk
    *(float4*)(AsH + arow * 40 + ac * 8) = rh;
    *(float4*)(AsL + arow * 40 + ac * 8) = rl;
    // prefetch next A chunk (consumed after the next barrier pair; stays in
    // flight across the lgkm-only barrier)
    if (k0 + 32 < KEFF) {
      rh = *(const float4*)(gah + k0 + 32);
      rl = *(const float4*)(gal + k0 + 32);
    }
    lds_barrier();

#pragma unroll
    for (int i = 0; i < 4; i++) {
      int row = i * 16 + l15;
      bf16x8 ah = *(const bf16x8*)(AsH + row * 40 + quad * 8);
      bf16x8 al = *(const bf16x8*)(AsL + row * 40 + quad * 8);
#pragma unroll
      for (int s = 0; s < 3; s++) {
        acc[i][s] = __builtin_amdgcn_mfma_f32_16x16x32_bf16(ah, bhf[s], acc[i][s], 0, 0, 0);
        acc[i][s] = __builtin_amdgcn_mfma_f32_16x16x32_bf16(al, bhf[s], acc[i][s], 0, 0, 0);
        acc[i][s] = __builtin_amdgcn_mfma_f32_16x16x32_bf16(ah, blf[s], acc[i][s], 0, 0, 0);
      }
    }
    lds_barrier();
  }

  float avg = *avg_ptr;
  int col = w * 16 + l15;
  float be0 = beff[col], be1 = beff[64 + col], be2 = beff[128 + col];
  float bi = bias[col];
  float ss = 0.f, sq = 0.f;
#pragma unroll
  for (int i = 0; i < 4; i++) {
#pragma unroll
    for (int r = 0; r < 4; r++) {
      int n = n0 + i * 16 + quad * 4 + r;
      if (n < N_NODES) {
        float ld = log_deg[n];
        float amp = ld / avg, att = avg / ld;
        float v = (acc[i][0][r] + be0) + amp * (acc[i][1][r] + be1)
                + att * (acc[i][2][r] + be2) + bi;
        h[(size_t)n * 64 + col] = v;
        ss += v; sq = fmaf(v, v, sq);
      }
    }
  }
  // reduce over quads (same col every 16 lanes)
  ss += __shfl_xor(ss, 16, 64); ss += __shfl_xor(ss, 32, 64);
  sq += __shfl_xor(sq, 16, 64); sq += __shfl_xor(sq, 32, 64);
  if (quad == 0) {
    atomicAdd(&bnacc[col], (double)ss);
    atomicAdd(&bnacc[64 + col], (double)sq);
  }
}

// ===================== fused BN finalize + apply =====================

__global__ __launch_bounds__(256) void apply_kernel(
    const float* __restrict__ h, const double* __restrict__ acc,
    const float* __restrict__ g, const float* __restrict__ bnb,
    float* __restrict__ x)
{
  __shared__ float smu[64], ssc[64];
  int tid = threadIdx.x;
  if (tid < 64) {
    double mu = acc[tid] / (double)N_NODES;
    double var = acc[64 + tid] / (double)N_NODES - mu * mu;
    double rstd = 1.0 / sqrt(var + 1e-5);
    smu[tid] = (float)mu;
    ssc[tid] = (float)(rstd * (double)g[tid]);
  }
  __syncthreads();
  int i4 = blockIdx.x * 256 + tid;   // float4 index, exact grid
  const float4* h4 = (const float4*)h;
  float4* x4 = (float4*)x;
  int c4 = (i4 & 15) * 4;
  float4 hv = h4[i4], xv = x4[i4];
  float4 bb = ((const float4*)bnb)[i4 & 15];
  float4 r;
  r.x = fmaxf((hv.x - smu[c4])     * ssc[c4]     + bb.x, 0.f) + xv.x;
  r.y = fmaxf((hv.y - smu[c4 + 1]) * ssc[c4 + 1] + bb.y, 0.f) + xv.y;
  r.z = fmaxf((hv.z - smu[c4 + 2]) * ssc[c4 + 2] + bb.z, 0.f) + xv.z;
  r.w = fmaxf((hv.w - smu[c4 + 3]) * ssc[c4 + 3] + bb.w, 0.f) + xv.w;
  x4[i4] = r;
}

// ===================== pooling + head =====================

__global__ __launch_bounds__(256) void pool_kernel(
    const float* __restrict__ x, const int* __restrict__ batch,
    float* __restrict__ gsum)
{
  int tid = threadIdx.x;
  int j = tid & 63, ri = tid >> 6;
  float acc = 0.f; int cur = -1;
  for (int k = 0; k < 16; k++) {
    int n = blockIdx.x * 64 + k * 4 + ri;
    if (n < N_NODES) {
      int b = batch[n];
      if (b != cur) {
        if (cur >= 0) atomicAdd(&gsum[cur * 64 + j], acc);
        cur = b; acc = 0.f;
      }
      acc += x[(size_t)n * 64 + j];
    }
  }
  if (cur >= 0) atomicAdd(&gsum[cur * 64 + j], acc);
}

// fc head v2: one block per graph (64 blocks x 64 threads). Weights staged
// into LDS with coalesced lane-varying loads; layer1 split 2 threads/output,
// layer2 4 threads/output, layer3 1 thread/output.
__global__ __launch_bounds__(64) void fc_kernel(
    const float* __restrict__ gsum, const int* __restrict__ gcnt,
    const float* __restrict__ w1, const float* __restrict__ b1,
    const float* __restrict__ w2, const float* __restrict__ b2,
    const float* __restrict__ w3, const float* __restrict__ b3,
    float* __restrict__ out)
{
  __shared__ float w1s[64 * 32], w2s[32 * 16], w3s[16 * 10];
  __shared__ float b1s[32], b2s[16], b3s[10];
  __shared__ float gvs[64], a1s[32], a2s[16];
  int g = blockIdx.x, tid = threadIdx.x;

#pragma unroll
  for (int i = 0; i < 32; i++) w1s[tid + 64 * i] = w1[tid + 64 * i];
#pragma unroll
  for (int i = 0; i < 8; i++)  w2s[tid + 64 * i] = w2[tid + 64 * i];
  { int i2 = tid; if (i2 < 160) w3s[i2] = w3[i2];
    i2 = tid + 64; if (i2 < 160) w3s[i2] = w3[i2];
    i2 = tid + 128; if (i2 < 160) w3s[i2] = w3[i2]; }
  if (tid < 32) b1s[tid] = b1[tid];
  if (tid < 16) b2s[tid] = b2[tid];
  if (tid < 10) b3s[tid] = b3[tid];
  float cnt = fmaxf((float)gcnt[g], 1.0f);
  gvs[tid] = gsum[g * 64 + tid] / cnt;
  __syncthreads();

  // layer 1: 64->32, 2 threads per output (j-halves), combine via shfl
  {
    int o = tid & 31, half = tid >> 5;
    float s = 0.f;
#pragma unroll
    for (int j = 0; j < 32; j++)
      s = fmaf(gvs[half * 32 + j], w1s[(half * 32 + j) * 32 + o], s);
    s += __shfl_xor(s, 32, 64);
    if (half == 0) a1s[o] = fmaxf(s + b1s[o], 0.f);
  }
  __syncthreads();

  // layer 2: 32->16, 4 threads per output (j-eighths)
  {
    int o = tid & 15, part = tid >> 4;
    float s = 0.f;
#pragma unroll
    for (int j = 0; j < 8; j++)
      s = fmaf(a1s[part * 8 + j], w2s[(part * 8 + j) * 16 + o], s);
    s += __shfl_xor(s, 16, 64);
    s += __shfl_xor(s, 32, 64);
    if (part == 0) a2s[o] = fmaxf(s + b2s[o], 0.f);
  }
  __syncthreads();

  // layer 3: 16->10, 1 thread per output
  if (tid < 10) {
    float s = b3s[tid];
#pragma unroll
    for (int j = 0; j < 16; j++) s = fmaf(a2s[j], w3s[j * 10 + tid], s);
    out[g * 10 + tid] = s;
  }
}

// ===================== launch =====================

extern "C" void kernel_launch(void* const* d_in, const int* in_sizes, int n_in,
                              void* d_out, int out_size, void* d_ws, size_t ws_size,
                              hipStream_t stream)
{
  (void)in_sizes; (void)n_in; (void)out_size; (void)ws_size;
  const float* xin    = (const float*)d_in[0];
  const int*   ei     = (const int*)d_in[1];
  const int*   batch  = (const int*)d_in[2];
  const float* eattr  = (const float*)d_in[3];
  const float* node_w = (const float*)d_in[4];
  const float* node_b = (const float*)d_in[5];
  const float* edge_w = (const float*)d_in[6];
  const float* edge_b = (const float*)d_in[7];
  const float* conv_w = (const float*)d_in[8];
  const float* conv_b = (const float*)d_in[9];
  const float* bn_g   = (const float*)d_in[10];
  const float* bn_b   = (const float*)d_in[11];
  const float* fc1_w  = (const float*)d_in[12];
  const float* fc1_b  = (const float*)d_in[13];
  const float* fc2_w  = (const float*)d_in[14];
  const float* fc2_b  = (const float*)d_in[15];
  const float* fc3_w  = (const float*)d_in[16];
  const float* fc3_b  = (const float*)d_in[17];
  float* out = (float*)d_out;
  const int* srcp = ei;
  const int* dstp = ei + N_EDGES;

  char* p = (char*)d_ws;
  auto alloc = [&](size_t b) { char* r = p; p += (b + 255) & ~(size_t)255; return (void*)r; };
  float*  x       = (float*)alloc((size_t)N_NODES * 64 * 4);
  float*  h       = (float*)alloc((size_t)N_NODES * 64 * 4);
  unsigned short* agg_h = (unsigned short*)alloc((size_t)N_NODES * KEFF * 2);
  unsigned short* agg_l = (unsigned short*)alloc((size_t)N_NODES * KEFF * 2);
  unsigned short* wh    = (unsigned short*)alloc((size_t)3 * 12 * 72 * 128 * 2);
  unsigned short* wl    = (unsigned short*)alloc((size_t)3 * 12 * 72 * 128 * 2);
  int2*   edata   = (int2*)alloc((size_t)N_EDGES * 8);
  int*    rank    = (int*)alloc((size_t)N_EDGES * 4);
  float*  beff    = (float*)alloc((size_t)3 * 3 * 64 * 4);
  int*    row_ptr = (int*)alloc((N_NODES + 1) * 4);
  int*    cnt     = (int*)alloc((size_t)N_NODES * 4);
  float*  log_deg = (float*)alloc((size_t)N_NODES * 4);
  int*    bsum    = (int*)alloc(256 * 4);
  int*    boff    = (int*)alloc(256 * 4);
  double* avgacc  = (double*)alloc(256);
  float*  avgf    = (float*)alloc(256);
  double* bnacc   = (double*)alloc(3 * 128 * 8);
  float*  gsum    = (float*)alloc((size_t)NGRAPH * 64 * 4);
  int*    gcnt    = (int*)alloc((size_t)NGRAPH * 4);
  unsigned short* ewh = (unsigned short*)alloc(1024 * 2);
  unsigned short* ewl = (unsigned short*)alloc(1024 * 2);

  zero_kernel<<<213, 256, 0, stream>>>(cnt, gsum, bnacc, avgacc);
  node_enc_kernel<<<12500, 256, 0, stream>>>(xin, node_w, node_b, x);
  count_kernel<<<3125, 256, 0, stream>>>(dstp, cnt, rank);
  scan_deg_kernel<<<196, 256, 0, stream>>>(cnt, bsum, log_deg, avgacc);
  scan_b_kernel<<<1, 256, 0, stream>>>(bsum, boff);
  scan_c_kernel<<<196, 256, 0, stream>>>(cnt, boff, row_ptr);
  fill_kernel<<<3125, 256, 0, stream>>>(srcp, dstp, rank, row_ptr, edata);
  avg_gb_kernel<<<1, 64, 0, stream>>>(avgacc, avgf, batch, gcnt);
  wprep_kernel<<<1296, 256, 0, stream>>>(conv_w, wh, wl);
  bprep_kernel<<<3, 192, 0, stream>>>(conv_w, beff);
  ewprep_kernel<<<1, 256, 0, stream>>>(edge_w, ewh, ewl);

  agg_e_kernel<<<AGG_E_BLOCKS, 256, 0, stream>>>(eattr, ewh, ewl, edge_b,
                                                 row_ptr, edata, agg_h, agg_l);

  for (int l = 0; l < 3; l++) {
    agg_x_kernel<<<12500, 256, 0, stream>>>(x, edata, row_ptr, agg_h, agg_l);
    gemm_kernel<<<782, 256, 0, stream>>>(agg_h, agg_l,
                                         wh + (size_t)l * 12 * 72 * 128,
                                         wl + (size_t)l * 12 * 72 * 128,
                                         beff + l * 192, conv_b + l * 64,
                                         log_deg, avgf, h, bnacc + l * 128);
    apply_kernel<<<3125, 256, 0, stream>>>(h, bnacc + l * 128, bn_g + l * 64,
                                           bn_b + l * 64, x);
  }

  pool_kernel<<<782, 256, 0, stream>>>(x, batch, gsum);
  fc_kernel<<<NGRAPH, 64, 0, stream>>>(gsum, gcnt, fc1_w, fc1_b, fc2_w, fc2_b,
                                       fc3_w, fc3_b, out);
}